// Round 1
// baseline (614.758 us; speedup 1.0000x reference)
//
#include <hip/hip_runtime.h>
#include <hip/hip_bf16.h>

#define BATCH 8
#define NH 12
#define DIM 768
#define HD 64
#define NQ 1568       // 8*14*14
#define TT 8
#define HH_ 14
#define WW_ 14
#define LK 392        // 8*7*7
#define LKP 416       // padded V^T row pitch (13*32), zero tail
#define SCALE 0.125f
#define EPS 1e-5f

// padded pool-input layout: [s][bh][pt 0..9][py 0..15][px 0..15][c]
#define PT 10
#define PPLANE 256            // 16*16
#define PVOL 2560             // PT*PPLANE
#define PS ((size_t)BATCH * NH * PVOL * HD)   // elems per s-third

typedef __bf16 bf16x8 __attribute__((ext_vector_type(8)));
typedef float f32x4 __attribute__((ext_vector_type(4)));

__device__ inline ushort f2bf(float f) {
  uint u = __float_as_uint(f);
  u += 0x7FFF + ((u >> 16) & 1);   // RNE
  return (ushort)(u >> 16);
}
__device__ inline float bf2f(ushort v) { return __uint_as_float((uint)v << 16); }
__device__ inline float bfl(uint u) { return __uint_as_float(u << 16); }
__device__ inline float bfh(uint u) { return __uint_as_float(u & 0xffff0000u); }

// async global->LDS, 16B per lane; LDS dest = wave-uniform base + lane*16
__device__ inline void gload_lds16(const ushort* g, ushort* l) {
  __builtin_amdgcn_global_load_lds(
      (const __attribute__((address_space(1))) void*)g,
      (__attribute__((address_space(3))) void*)l, 16, 0, 0);
}

// ---------------- zero fill ----------------
__global__ __launch_bounds__(256) void zero_kernel(uint4* __restrict__ p, int n16) {
  int i = blockIdx.x * 256 + threadIdx.x;
  int stride = gridDim.x * 256;
  for (; i < n16; i += stride) p[i] = make_uint4(0, 0, 0, 0);
}

// ---------------- cast fp32 -> bf16 ----------------
__global__ __launch_bounds__(256) void cast_bf16(const float* __restrict__ in,
                                                 ushort* __restrict__ outb, int n) {
  int i = (blockIdx.x * blockDim.x + threadIdx.x) * 4;
  if (i >= n) return;
  float4 v = *(const float4*)(in + i);
  ushort4 o = make_ushort4(f2bf(v.x), f2bf(v.y), f2bf(v.z), f2bf(v.w));
  *(ushort4*)(outb + i) = o;
}

// ---------------- transpose + cast: in[R][C] fp32 -> out[C][R] bf16 ----------------
__global__ __launch_bounds__(256) void transpose_cast(const float* __restrict__ in,
                                                      ushort* __restrict__ outb,
                                                      int R, int C) {
  __shared__ float tile[32][33];
  int tx = threadIdx.x & 31, ty = threadIdx.x >> 5;
  int bx = blockIdx.x * 32;
  int by = blockIdx.y * 32;
#pragma unroll
  for (int r = 0; r < 4; ++r)
    tile[ty + r * 8][tx] = in[(size_t)(by + ty + r * 8) * C + bx + tx];
  __syncthreads();
#pragma unroll
  for (int r = 0; r < 4; ++r)
    outb[(size_t)(bx + ty + r * 8) * R + by + tx] = f2bf(tile[tx][ty + r * 8]);
}

// ---------------- pool-weight transpose: [c][27] -> [tap][c], 3 tensors ----------------
__global__ __launch_bounds__(256) void wpool_transpose(const float* __restrict__ wq,
                                                       const float* __restrict__ wk,
                                                       const float* __restrict__ wv,
                                                       float* __restrict__ wT) {
  int i = blockIdx.x * blockDim.x + threadIdx.x;
  if (i >= 3 * 27 * 64) return;
  int s = i / (27 * 64), r = i % (27 * 64), tap = r / 64, c = r % 64;
  const float* src = (s == 0) ? wq : ((s == 1) ? wk : wv);
  wT[i] = src[c * 27 + tap];
}

// ---------------- bf16 MFMA GEMM (m97 structure: global_load_lds, linear LDS) ------
template<int EPI>
__global__ __launch_bounds__(256) void gemm_mfma(const ushort* __restrict__ A,
                                                 const ushort* __restrict__ Bt,
                                                 const float* __restrict__ bias,
                                                 float* __restrict__ outf,
                                                 ushort* __restrict__ outp,
                                                 int M, int N, int K) {
  __shared__ ushort As[128 * 32];   // linear, pitch 32 (required by global_load_lds)
  __shared__ ushort Bs[128 * 32];
  const int tid = threadIdx.x;
  const int wave = tid >> 6, lane = tid & 63;
  const int quad = lane >> 4, l16 = lane & 15;
  const int row0 = blockIdx.y * 128;
  const int col0 = blockIdx.x * 128;
  const int wm = (wave & 1) * 64;
  const int wn = (wave >> 1) * 64;

  f32x4 acc[4][4];
#pragma unroll
  for (int i = 0; i < 4; ++i)
#pragma unroll
    for (int j = 0; j < 4; ++j) acc[i][j] = (f32x4){0.f, 0.f, 0.f, 0.f};

  // staging geometry: wave w issue i covers rows i*64 + w*16 + (lane>>2), col (lane&3)*8
  const int srow = (wave << 4) + (lane >> 2);
  const int scol = (lane & 3) << 3;
  ushort* ldsA = As + wave * 512;      // + i*2048 for second issue
  ushort* ldsB = Bs + wave * 512;
  const ushort* gA = A + (size_t)(row0 + srow) * K + scol;
  const ushort* gB = Bt + (size_t)(col0 + srow) * K + scol;

  for (int k0 = 0; k0 < K; k0 += 32) {
    __syncthreads();                       // prev-tile reads complete
    gload_lds16(gA + k0, ldsA);
    gload_lds16(gA + (size_t)64 * K + k0, ldsA + 2048);
    gload_lds16(gB + k0, ldsB);
    gload_lds16(gB + (size_t)64 * K + k0, ldsB + 2048);
    __syncthreads();                       // drains vmcnt(0): tile visible
    bf16x8 af[4], bfr[4];
#pragma unroll
    for (int i = 0; i < 4; ++i)
      af[i] = *(const bf16x8*)&As[(wm + i * 16 + l16) * 32 + quad * 8];
#pragma unroll
    for (int j = 0; j < 4; ++j)
      bfr[j] = *(const bf16x8*)&Bs[(wn + j * 16 + l16) * 32 + quad * 8];
#pragma unroll
    for (int i = 0; i < 4; ++i)
#pragma unroll
      for (int j = 0; j < 4; ++j)
        acc[i][j] = __builtin_amdgcn_mfma_f32_16x16x32_bf16(af[i], bfr[j], acc[i][j], 0, 0, 0);
  }

#pragma unroll
  for (int i = 0; i < 4; ++i) {
#pragma unroll
    for (int j = 0; j < 4; ++j) {
      int col = col0 + wn + j * 16 + l16;
      float bv = bias[col];
#pragma unroll
      for (int r = 0; r < 4; ++r) {
        int row = row0 + wm + i * 16 + quad * 4 + r;
        float val = acc[i][j][r] + bv;
        if (EPI == 0) {
          outf[(size_t)row * N + col] = val;
        } else {
          int b = row / NQ, nn = row % NQ;
          int s = col / DIM, rr = col % DIM;
          int h = rr >> 6, cc = rr & 63;
          int t = nn / 196, r2 = nn % 196, y = r2 / 14, xx = r2 % 14;
          size_t pidx = (((size_t)s * BATCH * NH + b * NH + h) * PVOL
                         + (t + 1) * PPLANE + (y + 1) * 16 + (xx + 1)) * (size_t)HD + cc;
          outp[pidx] = f2bf(val);
        }
      }
    }
  }
}

// ---------------- padded depthwise pool + LayerNorm(64) -> bf16 ----------------
template<int SW, int VT>
__global__ __launch_bounds__(256) void pool_ln_pad(const ushort* __restrict__ in,
                                                   ushort* __restrict__ out,
                                                   const float* __restrict__ wT,
                                                   const float* __restrict__ g,
                                                   const float* __restrict__ bb,
                                                   int OH, int OW) {
  const int OL = 8 * OH * OW;
  const int wid = (blockIdx.x * blockDim.x + threadIdx.x) >> 6;
  const int lane = threadIdx.x & 63;
  const int total = BATCH * NH * OL;
  if (wid >= total) return;
  const int bh = wid / OL, opos = wid % OL;
  const int ot = opos / (OH * OW);
  const int r = opos % (OH * OW);
  const int oy = r / OW, ox = r % OW;
  const int c = lane;
  const ushort* base = in + ((size_t)bh * PVOL + ot * PPLANE + oy * SW * 16 + ox * SW) * HD + c;

  float v[27], wv[27];
#pragma unroll
  for (int dt = 0; dt < 3; ++dt)
#pragma unroll
    for (int dy = 0; dy < 3; ++dy)
#pragma unroll
      for (int dx = 0; dx < 3; ++dx) {
        int i = (dt * 3 + dy) * 3 + dx;
        v[i] = bf2f(base[(size_t)(dt * PPLANE + dy * 16 + dx) * HD]);
        wv[i] = wT[i * 64 + c];
      }
  float acc = 0.f;
#pragma unroll
  for (int i = 0; i < 27; ++i) acc += v[i] * wv[i];

  float s = acc;
#pragma unroll
  for (int off = 32; off; off >>= 1) s += __shfl_xor(s, off, 64);
  float mean = s * (1.f / 64.f);
  float d = acc - mean;
  float vs = d * d;
#pragma unroll
  for (int off = 32; off; off >>= 1) vs += __shfl_xor(vs, off, 64);
  float inv = rsqrtf(vs * (1.f / 64.f) + EPS);
  float res = d * inv * g[c] + bb[c];
  if (VT == 0) out[(size_t)wid * HD + c] = f2bf(res);
  else         out[((size_t)bh * HD + c) * LKP + opos] = f2bf(res);
}

// ---------------- rel-pos bias precompute (bf16 q) ----------------
__global__ __launch_bounds__(256) void rel_kernel(const ushort* __restrict__ qp,
                                                  const float* __restrict__ Rh,
                                                  const float* __restrict__ Rw,
                                                  const float* __restrict__ Rt,
                                                  float* __restrict__ rel) {
  const int idx = blockIdx.x * blockDim.x + threadIdx.x;
  const int total = BATCH * NH * NQ * 22;
  if (idx >= total) return;
  const int j = idx % 22;
  const int q = idx / 22;
  const int n = q % NQ;
  const int t = n / (HH_ * WW_);
  const int r = n % (HH_ * WW_);
  const int y = r / WW_, x = r % WW_;
  const float* R;
  if (j < 7)       R = Rh + (size_t)(y - 2 * j + 12) * HD;
  else if (j < 14) R = Rw + (size_t)(x - 2 * (j - 7) + 12) * HD;
  else             R = Rt + (size_t)(t - (j - 14) + 7) * HD;
  const ushort* qrow = qp + (size_t)q * HD;
  float acc = 0.f;
#pragma unroll 2
  for (int c = 0; c < HD; c += 8) {
    uint4 qa = *(const uint4*)(qrow + c);
    float4 r0 = *(const float4*)(R + c);
    float4 r1 = *(const float4*)(R + c + 4);
    acc += bfl(qa.x) * r0.x + bfh(qa.x) * r0.y + bfl(qa.y) * r0.z + bfh(qa.y) * r0.w;
    acc += bfl(qa.z) * r1.x + bfh(qa.z) * r1.y + bfl(qa.w) * r1.z + bfh(qa.w) * r1.w;
  }
  rel[(size_t)q * 24 + j] = acc;
}

// ---------------- MFMA attention: 32 queries/block ----
// V fragments fully prefetched into registers at kernel start (latency hides
// under QK phase; drained by barrier 1's implicit vmcnt wait).
// rel bias expanded once per block to 2-term form: sRel2[q][kyx<49] = h+w pair,
// sRel2[q][49+kt] = t term  -> logits do 2 LDS reads instead of 3.
__global__ __launch_bounds__(256, 3) void attn_mfma(const ushort* __restrict__ qp,
                                                 const ushort* __restrict__ kp,
                                                 const ushort* __restrict__ vT,
                                                 const float* __restrict__ rel,
                                                 ushort* __restrict__ outb) {
  __shared__ ushort sP[32][424];     // pitch 424: P-read (b128) spreads all banks
  __shared__ float sRel2[32][57];
  __shared__ float sMax[32][4];
  __shared__ float sSum[32][4];
  const int qb = blockIdx.x;        // 0..48
  const int bh = blockIdx.y;        // 0..95
  const int b = bh / NH, h = bh % NH;
  const int tid = threadIdx.x;
  const int w = tid >> 6, lane = tid & 63;
  const int quad = lane >> 4, l16 = lane & 15;
  const int q0 = qb * 32;

  // V prefetch: all 13 fragments, issued before anything else
  const ushort* vrow = vT + ((size_t)bh * HD + w * 16 + l16) * LKP;
  bf16x8 vf[13];
#pragma unroll
  for (int s = 0; s < 13; ++s)
    vf[s] = *(const bf16x8*)(vrow + s * 32 + quad * 8);

  // Q A-fragments direct from global (same for all waves; 4x redundant, tiny)
  const ushort* qbase = qp + ((size_t)bh * NQ + q0) * HD;
  bf16x8 af[2][2];
#pragma unroll
  for (int t = 0; t < 2; ++t) {
    af[t][0] = *(const bf16x8*)(qbase + (size_t)(t * 16 + l16) * HD + quad * 8);
    af[t][1] = *(const bf16x8*)(qbase + (size_t)(t * 16 + l16) * HD + 32 + quad * 8);
  }

  // rel expansion directly from global (L2-hot): 1824 entries over 256 threads
  const float* relbase = rel + ((size_t)bh * NQ + q0) * 24;
  for (int e = tid; e < 32 * 57; e += 256) {
    int qq = e / 57, i = e - qq * 57;
    float vv;
    if (i < 49) vv = relbase[qq * 24 + i / 7] + relbase[qq * 24 + 7 + i % 7];
    else        vv = relbase[qq * 24 + 14 + (i - 49)];
    sRel2[qq][i] = vv;
  }
  // zero P pad cols 400..415
  if (tid < 64) {
    int row = tid >> 1, seg = tid & 1;
    *(uint4*)&sP[row][400 + seg * 8] = make_uint4(0, 0, 0, 0);
  }

  f32x4 acc[7][2];
#pragma unroll
  for (int c = 0; c < 7; ++c)
#pragma unroll
    for (int t = 0; t < 2; ++t) acc[c][t] = (f32x4){0.f, 0.f, 0.f, 0.f};

  // ---- QK^T: wave w owns tiles tg = c*4+w; K B-fragments direct from global ----
  const ushort* kbase = kp + (size_t)bh * LK * HD;
#pragma unroll
  for (int c = 0; c < 7; ++c) {
    int tg = c * 4 + w;
    if (tg < 25) {
      int kg = tg * 16 + l16;
      int kgc = kg < LK ? kg : (LK - 1);   // clamp; masked below
      const ushort* krow = kbase + (size_t)kgc * HD;
      bf16x8 b0 = *(const bf16x8*)(krow + quad * 8);
      bf16x8 b1 = *(const bf16x8*)(krow + 32 + quad * 8);
#pragma unroll
      for (int t = 0; t < 2; ++t) {
        acc[c][t] = __builtin_amdgcn_mfma_f32_16x16x32_bf16(af[t][0], b0, acc[c][t], 0, 0, 0);
        acc[c][t] = __builtin_amdgcn_mfma_f32_16x16x32_bf16(af[t][1], b1, acc[c][t], 0, 0, 0);
      }
    }
  }
  __syncthreads();   // barrier 1: sRel2/sP-pad visible; drains all prefetches

  // ---- logits: scale + rel bias (2 reads) ----
#pragma unroll
  for (int c = 0; c < 7; ++c) {
    int tg = c * 4 + w;
    int kg = tg * 16 + l16;
    if (tg < 25 && kg < LK) {
      int kt = kg / 49, kyx = kg % 49;
#pragma unroll
      for (int t = 0; t < 2; ++t)
#pragma unroll
        for (int r = 0; r < 4; ++r) {
          int q = t * 16 + quad * 4 + r;
          acc[c][t][r] = acc[c][t][r] * SCALE + sRel2[q][kyx] + sRel2[q][49 + kt];
        }
    } else {
#pragma unroll
      for (int t = 0; t < 2; ++t)
#pragma unroll
        for (int r = 0; r < 4; ++r) acc[c][t][r] = -1e30f;
    }
  }

  // ---- row max: reduce over l16, exchange across waves ----
  float pmax[2][4];
#pragma unroll
  for (int t = 0; t < 2; ++t)
#pragma unroll
    for (int r = 0; r < 4; ++r) {
      float m = acc[0][t][r];
#pragma unroll
      for (int c = 1; c < 7; ++c) m = fmaxf(m, acc[c][t][r]);
#pragma unroll
      for (int off = 1; off < 16; off <<= 1) m = fmaxf(m, __shfl_xor(m, off, 64));
      pmax[t][r] = m;
    }
  if (l16 == 0) {
#pragma unroll
    for (int t = 0; t < 2; ++t)
#pragma unroll
      for (int r = 0; r < 4; ++r) sMax[t * 16 + quad * 4 + r][w] = pmax[t][r];
  }
  __syncthreads();   // barrier 2

  float M[2][4];
#pragma unroll
  for (int t = 0; t < 2; ++t)
#pragma unroll
    for (int r = 0; r < 4; ++r) {
      float4 mm = *(float4*)&sMax[t * 16 + quad * 4 + r][0];
      M[t][r] = fmaxf(fmaxf(mm.x, mm.y), fmaxf(mm.z, mm.w));
    }

  // ---- exp, partial sums, P write ----
  float psum[2][4];
#pragma unroll
  for (int t = 0; t < 2; ++t)
#pragma unroll
    for (int r = 0; r < 4; ++r) psum[t][r] = 0.f;
#pragma unroll
  for (int c = 0; c < 7; ++c) {
#pragma unroll
    for (int t = 0; t < 2; ++t)
#pragma unroll
      for (int r = 0; r < 4; ++r) {
        float e = __expf(acc[c][t][r] - M[t][r]);
        acc[c][t][r] = e;
        psum[t][r] += e;
      }
  }
#pragma unroll
  for (int t = 0; t < 2; ++t)
#pragma unroll
    for (int r = 0; r < 4; ++r) {
      float s = psum[t][r];
#pragma unroll
      for (int off = 1; off < 16; off <<= 1) s += __shfl_xor(s, off, 64);
      psum[t][r] = s;
    }
  if (l16 == 0) {
#pragma unroll
    for (int t = 0; t < 2; ++t)
#pragma unroll
      for (int r = 0; r < 4; ++r) sSum[t * 16 + quad * 4 + r][w] = psum[t][r];
  }
#pragma unroll
  for (int c = 0; c < 7; ++c) {
    int tg = c * 4 + w;
    if (tg < 25) {
      int kg = tg * 16 + l16;
#pragma unroll
      for (int t = 0; t < 2; ++t)
#pragma unroll
        for (int r = 0; r < 4; ++r)
          sP[t * 16 + quad * 4 + r][kg] = f2bf(acc[c][t][r]);
    }
  }
  __syncthreads();   // barrier 3

  float rinv[2][4];
#pragma unroll
  for (int t = 0; t < 2; ++t)
#pragma unroll
    for (int r = 0; r < 4; ++r) {
      float4 ss = *(float4*)&sSum[t * 16 + quad * 4 + r][0];
      rinv[t][r] = 1.f / (ss.x + ss.y + ss.z + ss.w);
    }

  // ---- PV: V^T fragments already in registers (vf) ----
  f32x4 oacc[2];
  oacc[0] = (f32x4){0.f, 0.f, 0.f, 0.f};
  oacc[1] = (f32x4){0.f, 0.f, 0.f, 0.f};
#pragma unroll
  for (int s = 0; s < 13; ++s) {
    int kb = s * 32;
#pragma unroll
    for (int t = 0; t < 2; ++t) {
      bf16x8 pa = *(const bf16x8*)&sP[t * 16 + l16][kb + quad * 8];
      oacc[t] = __builtin_amdgcn_mfma_f32_16x16x32_bf16(pa, vf[s], oacc[t], 0, 0, 0);
    }
  }

#pragma unroll
  for (int t = 0; t < 2; ++t)
#pragma unroll
    for (int r = 0; r < 4; ++r) {
      int q = q0 + t * 16 + quad * 4 + r;
      outb[((size_t)b * NQ + q) * DIM + h * HD + w * 16 + l16] = f2bf(oacc[t][r] * rinv[t][r]);
    }
}

// ---------------- launch ----------------
extern "C" void kernel_launch(void* const* d_in, const int* in_sizes, int n_in,
                              void* d_out, int out_size, void* d_ws, size_t ws_size,
                              hipStream_t stream) {
  const float* x        = (const float*)d_in[0];
  const float* w_qkv    = (const float*)d_in[1];
  const float* b_qkv    = (const float*)d_in[2];
  const float* pool_q_w = (const float*)d_in[3];
  const float* pool_k_w = (const float*)d_in[4];
  const float* pool_v_w = (const float*)d_in[5];
  const float* norm_q_g = (const float*)d_in[6];
  const float* norm_q_b = (const float*)d_in[7];
  const float* norm_k_g = (const float*)d_in[8];
  const float* norm_k_b = (const float*)d_in[9];
  const float* norm_v_g = (const float*)d_in[10];
  const float* norm_v_b = (const float*)d_in[11];
  const float* rel_h    = (const float*)d_in[12];
  const float* rel_w    = (const float*)d_in[13];
  const float* rel_t    = (const float*)d_in[14];
  const float* w_proj   = (const float*)d_in[15];
  const float* b_proj   = (const float*)d_in[16];
  float* out = (float*)d_out;

  const size_t NT  = (size_t)BATCH * NH * NQ * HD;
  const size_t LKT = (size_t)BATCH * NH * LK * HD;
  const size_t LKV = (size_t)BATCH * NH * HD * LKP;   // padded V^T
  const size_t RELN = (size_t)BATCH * NH * NQ * 24;

  ushort* padQ = (ushort*)d_ws;                 // 3*PS bf16
  ushort* qpb  = padQ + 3 * PS;                 // NT bf16
  ushort* kpb  = qpb + NT;                      // LKT bf16
  ushort* vTb  = kpb + LKT;                     // LKV bf16 ([bh][c][kpos], pitch LKP)
  float*  relb = (float*)(vTb + LKV);           // RELN fp32
  ushort* wqkvT = (ushort*)(relb + RELN);
  ushort* wprojT = wqkvT + (size_t)DIM * 3 * DIM;
  float*  wpoolT = (float*)(wprojT + (size_t)DIM * DIM);
  ushort* xb = qpb;                   // overlay: dead before pool writes qpb
  ushort* attn_outb = padQ;           // overlay: padQ dead after pools

  const int M = BATCH * NQ;  // 12544

  zero_kernel<<<2048, 256, 0, stream>>>((uint4*)padQ, (int)(3 * PS * 2 / 16));
  zero_kernel<<<256, 256, 0, stream>>>((uint4*)vTb, (int)(LKV * 2 / 16));
  {
    int n = M * DIM;
    cast_bf16<<<(n / 4 + 255) / 256, 256, 0, stream>>>(x, xb, n);
    transpose_cast<<<dim3(3 * DIM / 32, DIM / 32), 256, 0, stream>>>(w_qkv, wqkvT, DIM, 3 * DIM);
    transpose_cast<<<dim3(DIM / 32, DIM / 32), 256, 0, stream>>>(w_proj, wprojT, DIM, DIM);
    wpool_transpose<<<(3 * 27 * 64 + 255) / 256, 256, 0, stream>>>(
        pool_q_w, pool_k_w, pool_v_w, wpoolT);
  }

  gemm_mfma<1><<<dim3(3 * DIM / 128, M / 128), 256, 0, stream>>>(
      xb, wqkvT, b_qkv, nullptr, padQ, M, 3 * DIM, DIM);

  {
    int wq = BATCH * NH * NQ;
    pool_ln_pad<1, 0><<<(wq + 3) / 4, 256, 0, stream>>>(
        padQ, qpb, wpoolT, norm_q_g, norm_q_b, 14, 14);
    int wk = BATCH * NH * LK;
    pool_ln_pad<2, 0><<<(wk + 3) / 4, 256, 0, stream>>>(
        padQ + PS, kpb, wpoolT + 27 * 64, norm_k_g, norm_k_b, 7, 7);
    pool_ln_pad<2, 1><<<(wk + 3) / 4, 256, 0, stream>>>(
        padQ + 2 * PS, vTb, wpoolT + 2 * 27 * 64, norm_v_g, norm_v_b, 7, 7);
  }

  {
    int total = BATCH * NH * NQ * 22;
    rel_kernel<<<(total + 255) / 256, 256, 0, stream>>>(qpb, rel_h, rel_w, rel_t, relb);
  }

  attn_mfma<<<dim3(NQ / 32, BATCH * NH), 256, 0, stream>>>(qpb, kpb, vTb, relb, attn_outb);

  gemm_mfma<0><<<dim3(DIM / 128, M / 128), 256, 0, stream>>>(
      attn_outb, wprojT, b_proj, out, nullptr, M, DIM, DIM);
}

// Round 2
// 612.040 us; speedup vs baseline: 1.0044x; 1.0044x over previous
//
#include <hip/hip_runtime.h>
#include <hip/hip_bf16.h>

#define BATCH 8
#define NH 12
#define DIM 768
#define HD 64
#define NQ 1568       // 8*14*14
#define TT 8
#define HH_ 14
#define WW_ 14
#define LK 392        // 8*7*7
#define LKP 416       // padded V^T row pitch (13*32), zero tail
#define SCALE 0.125f
#define EPS 1e-5f

// padded pool-input layout: [s][bh][pt 0..9][py 0..15][px 0..15][c]
#define PT 10
#define PPLANE 256            // 16*16
#define PVOL 2560             // PT*PPLANE
#define PS ((size_t)BATCH * NH * PVOL * HD)   // elems per s-third

typedef __bf16 bf16x8 __attribute__((ext_vector_type(8)));
typedef float f32x4 __attribute__((ext_vector_type(4)));

__device__ inline ushort f2bf(float f) {
  uint u = __float_as_uint(f);
  u += 0x7FFF + ((u >> 16) & 1);   // RNE
  return (ushort)(u >> 16);
}
__device__ inline float bf2f(ushort v) { return __uint_as_float((uint)v << 16); }
__device__ inline float bfl(uint u) { return __uint_as_float(u << 16); }
__device__ inline float bfh(uint u) { return __uint_as_float(u & 0xffff0000u); }

// async global->LDS, 16B per lane; LDS dest = wave-uniform base + lane*16
__device__ inline void gload_lds16(const ushort* g, ushort* l) {
  __builtin_amdgcn_global_load_lds(
      (const __attribute__((address_space(1))) void*)g,
      (__attribute__((address_space(3))) void*)l, 16, 0, 0);
}

// ---------------- zero fill ----------------
__global__ __launch_bounds__(256) void zero_kernel(uint4* __restrict__ p, int n16) {
  int i = blockIdx.x * 256 + threadIdx.x;
  int stride = gridDim.x * 256;
  for (; i < n16; i += stride) p[i] = make_uint4(0, 0, 0, 0);
}

// ---------------- cast fp32 -> bf16 ----------------
__global__ __launch_bounds__(256) void cast_bf16(const float* __restrict__ in,
                                                 ushort* __restrict__ outb, int n) {
  int i = (blockIdx.x * blockDim.x + threadIdx.x) * 4;
  if (i >= n) return;
  float4 v = *(const float4*)(in + i);
  ushort4 o = make_ushort4(f2bf(v.x), f2bf(v.y), f2bf(v.z), f2bf(v.w));
  *(ushort4*)(outb + i) = o;
}

// ---------------- transpose + cast: in[R][C] fp32 -> out[C][R] bf16 ----------------
__global__ __launch_bounds__(256) void transpose_cast(const float* __restrict__ in,
                                                      ushort* __restrict__ outb,
                                                      int R, int C) {
  __shared__ float tile[32][33];
  int tx = threadIdx.x & 31, ty = threadIdx.x >> 5;
  int bx = blockIdx.x * 32;
  int by = blockIdx.y * 32;
#pragma unroll
  for (int r = 0; r < 4; ++r)
    tile[ty + r * 8][tx] = in[(size_t)(by + ty + r * 8) * C + bx + tx];
  __syncthreads();
#pragma unroll
  for (int r = 0; r < 4; ++r)
    outb[(size_t)(bx + ty + r * 8) * R + by + tx] = f2bf(tile[tx][ty + r * 8]);
}

// ---------------- pool-weight transpose: [c][27] -> [tap][c], 3 tensors ----------------
__global__ __launch_bounds__(256) void wpool_transpose(const float* __restrict__ wq,
                                                       const float* __restrict__ wk,
                                                       const float* __restrict__ wv,
                                                       float* __restrict__ wT) {
  int i = blockIdx.x * blockDim.x + threadIdx.x;
  if (i >= 3 * 27 * 64) return;
  int s = i / (27 * 64), r = i % (27 * 64), tap = r / 64, c = r % 64;
  const float* src = (s == 0) ? wq : ((s == 1) ? wk : wv);
  wT[i] = src[c * 27 + tap];
}

// ---------------- bf16 MFMA GEMM (m97 structure: global_load_lds, linear LDS) ------
template<int EPI>
__global__ __launch_bounds__(256) void gemm_mfma(const ushort* __restrict__ A,
                                                 const ushort* __restrict__ Bt,
                                                 const float* __restrict__ bias,
                                                 float* __restrict__ outf,
                                                 ushort* __restrict__ outp,
                                                 int M, int N, int K) {
  __shared__ ushort As[128 * 32];   // linear, pitch 32 (required by global_load_lds)
  __shared__ ushort Bs[128 * 32];
  const int tid = threadIdx.x;
  const int wave = tid >> 6, lane = tid & 63;
  const int quad = lane >> 4, l16 = lane & 15;
  const int row0 = blockIdx.y * 128;
  const int col0 = blockIdx.x * 128;
  const int wm = (wave & 1) * 64;
  const int wn = (wave >> 1) * 64;

  f32x4 acc[4][4];
#pragma unroll
  for (int i = 0; i < 4; ++i)
#pragma unroll
    for (int j = 0; j < 4; ++j) acc[i][j] = (f32x4){0.f, 0.f, 0.f, 0.f};

  // staging geometry: wave w issue i covers rows i*64 + w*16 + (lane>>2), col (lane&3)*8
  const int srow = (wave << 4) + (lane >> 2);
  const int scol = (lane & 3) << 3;
  ushort* ldsA = As + wave * 512;      // + i*2048 for second issue
  ushort* ldsB = Bs + wave * 512;
  const ushort* gA = A + (size_t)(row0 + srow) * K + scol;
  const ushort* gB = Bt + (size_t)(col0 + srow) * K + scol;

  for (int k0 = 0; k0 < K; k0 += 32) {
    __syncthreads();                       // prev-tile reads complete
    gload_lds16(gA + k0, ldsA);
    gload_lds16(gA + (size_t)64 * K + k0, ldsA + 2048);
    gload_lds16(gB + k0, ldsB);
    gload_lds16(gB + (size_t)64 * K + k0, ldsB + 2048);
    __syncthreads();                       // drains vmcnt(0): tile visible
    bf16x8 af[4], bfr[4];
#pragma unroll
    for (int i = 0; i < 4; ++i)
      af[i] = *(const bf16x8*)&As[(wm + i * 16 + l16) * 32 + quad * 8];
#pragma unroll
    for (int j = 0; j < 4; ++j)
      bfr[j] = *(const bf16x8*)&Bs[(wn + j * 16 + l16) * 32 + quad * 8];
#pragma unroll
    for (int i = 0; i < 4; ++i)
#pragma unroll
      for (int j = 0; j < 4; ++j)
        acc[i][j] = __builtin_amdgcn_mfma_f32_16x16x32_bf16(af[i], bfr[j], acc[i][j], 0, 0, 0);
  }

#pragma unroll
  for (int i = 0; i < 4; ++i) {
#pragma unroll
    for (int j = 0; j < 4; ++j) {
      int col = col0 + wn + j * 16 + l16;
      float bv = bias[col];
#pragma unroll
      for (int r = 0; r < 4; ++r) {
        int row = row0 + wm + i * 16 + quad * 4 + r;
        float val = acc[i][j][r] + bv;
        if (EPI == 0) {
          outf[(size_t)row * N + col] = val;
        } else {
          int b = row / NQ, nn = row % NQ;
          int s = col / DIM, rr = col % DIM;
          int h = rr >> 6, cc = rr & 63;
          int t = nn / 196, r2 = nn % 196, y = r2 / 14, xx = r2 % 14;
          size_t pidx = (((size_t)s * BATCH * NH + b * NH + h) * PVOL
                         + (t + 1) * PPLANE + (y + 1) * 16 + (xx + 1)) * (size_t)HD + cc;
          outp[pidx] = f2bf(val);
        }
      }
    }
  }
}

// ---------------- padded depthwise pool + LayerNorm(64) -> bf16 ----------------
template<int SW, int VT>
__global__ __launch_bounds__(256) void pool_ln_pad(const ushort* __restrict__ in,
                                                   ushort* __restrict__ out,
                                                   const float* __restrict__ wT,
                                                   const float* __restrict__ g,
                                                   const float* __restrict__ bb,
                                                   int OH, int OW) {
  const int OL = 8 * OH * OW;
  const int wid = (blockIdx.x * blockDim.x + threadIdx.x) >> 6;
  const int lane = threadIdx.x & 63;
  const int total = BATCH * NH * OL;
  if (wid >= total) return;
  const int bh = wid / OL, opos = wid % OL;
  const int ot = opos / (OH * OW);
  const int r = opos % (OH * OW);
  const int oy = r / OW, ox = r % OW;
  const int c = lane;
  const ushort* base = in + ((size_t)bh * PVOL + ot * PPLANE + oy * SW * 16 + ox * SW) * HD + c;

  float v[27], wv[27];
#pragma unroll
  for (int dt = 0; dt < 3; ++dt)
#pragma unroll
    for (int dy = 0; dy < 3; ++dy)
#pragma unroll
      for (int dx = 0; dx < 3; ++dx) {
        int i = (dt * 3 + dy) * 3 + dx;
        v[i] = bf2f(base[(size_t)(dt * PPLANE + dy * 16 + dx) * HD]);
        wv[i] = wT[i * 64 + c];
      }
  float acc = 0.f;
#pragma unroll
  for (int i = 0; i < 27; ++i) acc += v[i] * wv[i];

  float s = acc;
#pragma unroll
  for (int off = 32; off; off >>= 1) s += __shfl_xor(s, off, 64);
  float mean = s * (1.f / 64.f);
  float d = acc - mean;
  float vs = d * d;
#pragma unroll
  for (int off = 32; off; off >>= 1) vs += __shfl_xor(vs, off, 64);
  float inv = rsqrtf(vs * (1.f / 64.f) + EPS);
  float res = d * inv * g[c] + bb[c];
  if (VT == 0) out[(size_t)wid * HD + c] = f2bf(res);
  else         out[((size_t)bh * HD + c) * LKP + opos] = f2bf(res);
}

// ---------------- rel-pos bias precompute (bf16 q) ----------------
__global__ __launch_bounds__(256) void rel_kernel(const ushort* __restrict__ qp,
                                                  const float* __restrict__ Rh,
                                                  const float* __restrict__ Rw,
                                                  const float* __restrict__ Rt,
                                                  float* __restrict__ rel) {
  const int idx = blockIdx.x * blockDim.x + threadIdx.x;
  const int total = BATCH * NH * NQ * 22;
  if (idx >= total) return;
  const int j = idx % 22;
  const int q = idx / 22;
  const int n = q % NQ;
  const int t = n / (HH_ * WW_);
  const int r = n % (HH_ * WW_);
  const int y = r / WW_, x = r % WW_;
  const float* R;
  if (j < 7)       R = Rh + (size_t)(y - 2 * j + 12) * HD;
  else if (j < 14) R = Rw + (size_t)(x - 2 * (j - 7) + 12) * HD;
  else             R = Rt + (size_t)(t - (j - 14) + 7) * HD;
  const ushort* qrow = qp + (size_t)q * HD;
  float acc = 0.f;
#pragma unroll 2
  for (int c = 0; c < HD; c += 8) {
    uint4 qa = *(const uint4*)(qrow + c);
    float4 r0 = *(const float4*)(R + c);
    float4 r1 = *(const float4*)(R + c + 4);
    acc += bfl(qa.x) * r0.x + bfh(qa.x) * r0.y + bfl(qa.y) * r0.z + bfh(qa.y) * r0.w;
    acc += bfl(qa.z) * r1.x + bfh(qa.z) * r1.y + bfl(qa.w) * r1.z + bfh(qa.w) * r1.w;
  }
  rel[(size_t)q * 24 + j] = acc;
}

// ---------------- MFMA attention: 32 queries/block ----
// rel bias expanded per block, TRANSPOSED: sRel2T[i<49][q] = h+w pair for kyx=i,
// sRel2T[49+kt][q] = t term. Logits read 4 q-rows with ONE ds_read_b128 each
// (2 reads per fragment instead of 8 scalar reads). Pitch 34: bank stride 2
// per kyx row -> <=2-way conflict (free). V loads stay inline in the PV loop
// (register prefetch spilled to scratch in the previous round: WRITE_SIZE 6x).
__global__ __launch_bounds__(256) void attn_mfma(const ushort* __restrict__ qp,
                                                 const ushort* __restrict__ kp,
                                                 const ushort* __restrict__ vT,
                                                 const float* __restrict__ rel,
                                                 ushort* __restrict__ outb) {
  __shared__ ushort sP[32][424];     // pitch 424: P-read (b128) spreads all banks
  __shared__ float sRel2T[57][34];
  __shared__ float sMax[32][4];
  __shared__ float sSum[32][4];
  const int qb = blockIdx.x;        // 0..48
  const int bh = blockIdx.y;        // 0..95
  const int b = bh / NH, h = bh % NH;
  const int tid = threadIdx.x;
  const int w = tid >> 6, lane = tid & 63;
  const int quad = lane >> 4, l16 = lane & 15;
  const int q0 = qb * 32;

  // Q A-fragments direct from global (same for all waves; 4x redundant, tiny)
  const ushort* qbase = qp + ((size_t)bh * NQ + q0) * HD;
  bf16x8 af[2][2];
#pragma unroll
  for (int t = 0; t < 2; ++t) {
    af[t][0] = *(const bf16x8*)(qbase + (size_t)(t * 16 + l16) * HD + quad * 8);
    af[t][1] = *(const bf16x8*)(qbase + (size_t)(t * 16 + l16) * HD + 32 + quad * 8);
  }

  // rel expansion directly from global (L2-hot): 57*32 entries over 256 threads
  const float* relbase = rel + ((size_t)bh * NQ + q0) * 24;
  for (int e = tid; e < 57 * 32; e += 256) {
    int i = e >> 5, qq = e & 31;
    float vv;
    if (i < 49) vv = relbase[qq * 24 + i / 7] + relbase[qq * 24 + 7 + i % 7];
    else        vv = relbase[qq * 24 + 14 + (i - 49)];
    sRel2T[i][qq] = vv;
  }
  // zero P pad cols 400..415
  if (tid < 64) {
    int row = tid >> 1, seg = tid & 1;
    *(uint4*)&sP[row][400 + seg * 8] = make_uint4(0, 0, 0, 0);
  }

  f32x4 acc[7][2];
#pragma unroll
  for (int c = 0; c < 7; ++c)
#pragma unroll
    for (int t = 0; t < 2; ++t) acc[c][t] = (f32x4){0.f, 0.f, 0.f, 0.f};

  // ---- QK^T: wave w owns tiles tg = c*4+w; K B-fragments direct from global ----
  const ushort* kbase = kp + (size_t)bh * LK * HD;
#pragma unroll
  for (int c = 0; c < 7; ++c) {
    int tg = c * 4 + w;
    if (tg < 25) {
      int kg = tg * 16 + l16;
      int kgc = kg < LK ? kg : (LK - 1);   // clamp; masked below
      const ushort* krow = kbase + (size_t)kgc * HD;
      bf16x8 b0 = *(const bf16x8*)(krow + quad * 8);
      bf16x8 b1 = *(const bf16x8*)(krow + 32 + quad * 8);
#pragma unroll
      for (int t = 0; t < 2; ++t) {
        acc[c][t] = __builtin_amdgcn_mfma_f32_16x16x32_bf16(af[t][0], b0, acc[c][t], 0, 0, 0);
        acc[c][t] = __builtin_amdgcn_mfma_f32_16x16x32_bf16(af[t][1], b1, acc[c][t], 0, 0, 0);
      }
    }
  }
  __syncthreads();   // barrier 1: sRel2T (and sP pad) visible

  // ---- logits: scale + rel bias (two b128 reads per 16x16 fragment) ----
#pragma unroll
  for (int c = 0; c < 7; ++c) {
    int tg = c * 4 + w;
    int kg = tg * 16 + l16;
    if (tg < 25) {
      int kgc = kg < LK ? kg : 0;
      int kt = kgc / 49, kyx = kgc % 49;
      bool ok = kg < LK;
#pragma unroll
      for (int t = 0; t < 2; ++t) {
        f32x4 byx = *(const f32x4*)&sRel2T[kyx][t * 16 + quad * 4];
        f32x4 bt  = *(const f32x4*)&sRel2T[49 + kt][t * 16 + quad * 4];
#pragma unroll
        for (int r = 0; r < 4; ++r)
          acc[c][t][r] = ok ? (acc[c][t][r] * SCALE + byx[r] + bt[r]) : -1e30f;
      }
    } else {
#pragma unroll
      for (int t = 0; t < 2; ++t)
#pragma unroll
        for (int r = 0; r < 4; ++r) acc[c][t][r] = -1e30f;
    }
  }

  // ---- row max: reduce over l16, exchange across waves ----
  float pmax[2][4];
#pragma unroll
  for (int t = 0; t < 2; ++t)
#pragma unroll
    for (int r = 0; r < 4; ++r) {
      float m = acc[0][t][r];
#pragma unroll
      for (int c = 1; c < 7; ++c) m = fmaxf(m, acc[c][t][r]);
#pragma unroll
      for (int off = 1; off < 16; off <<= 1) m = fmaxf(m, __shfl_xor(m, off, 64));
      pmax[t][r] = m;
    }
  if (l16 == 0) {
#pragma unroll
    for (int t = 0; t < 2; ++t)
#pragma unroll
      for (int r = 0; r < 4; ++r) sMax[t * 16 + quad * 4 + r][w] = pmax[t][r];
  }
  __syncthreads();   // barrier 2

  float M[2][4];
#pragma unroll
  for (int t = 0; t < 2; ++t)
#pragma unroll
    for (int r = 0; r < 4; ++r) {
      float4 mm = *(float4*)&sMax[t * 16 + quad * 4 + r][0];
      M[t][r] = fmaxf(fmaxf(mm.x, mm.y), fmaxf(mm.z, mm.w));
    }

  // ---- exp, partial sums, P write ----
  float psum[2][4];
#pragma unroll
  for (int t = 0; t < 2; ++t)
#pragma unroll
    for (int r = 0; r < 4; ++r) psum[t][r] = 0.f;
#pragma unroll
  for (int c = 0; c < 7; ++c) {
#pragma unroll
    for (int t = 0; t < 2; ++t)
#pragma unroll
      for (int r = 0; r < 4; ++r) {
        float e = __expf(acc[c][t][r] - M[t][r]);
        acc[c][t][r] = e;
        psum[t][r] += e;
      }
  }
#pragma unroll
  for (int t = 0; t < 2; ++t)
#pragma unroll
    for (int r = 0; r < 4; ++r) {
      float s = psum[t][r];
#pragma unroll
      for (int off = 1; off < 16; off <<= 1) s += __shfl_xor(s, off, 64);
      psum[t][r] = s;
    }
  if (l16 == 0) {
#pragma unroll
    for (int t = 0; t < 2; ++t)
#pragma unroll
      for (int r = 0; r < 4; ++r) sSum[t * 16 + quad * 4 + r][w] = psum[t][r];
  }
#pragma unroll
  for (int c = 0; c < 7; ++c) {
    int tg = c * 4 + w;
    if (tg < 25) {
      int kg = tg * 16 + l16;
#pragma unroll
      for (int t = 0; t < 2; ++t)
#pragma unroll
        for (int r = 0; r < 4; ++r)
          sP[t * 16 + quad * 4 + r][kg] = f2bf(acc[c][t][r]);
    }
  }
  __syncthreads();   // barrier 3

  float rinv[2][4];
#pragma unroll
  for (int t = 0; t < 2; ++t)
#pragma unroll
    for (int r = 0; r < 4; ++r) {
      float4 ss = *(float4*)&sSum[t * 16 + quad * 4 + r][0];
      rinv[t][r] = 1.f / (ss.x + ss.y + ss.z + ss.w);
    }

  // ---- PV: V^T B-fragments direct from global (padded pitch LKP, zero tail) ----
  f32x4 oacc[2];
  oacc[0] = (f32x4){0.f, 0.f, 0.f, 0.f};
  oacc[1] = (f32x4){0.f, 0.f, 0.f, 0.f};
  const ushort* vrow = vT + ((size_t)bh * HD + w * 16 + l16) * LKP;
#pragma unroll
  for (int s = 0; s < 13; ++s) {
    int kb = s * 32;
    bf16x8 vb = *(const bf16x8*)(vrow + kb + quad * 8);
#pragma unroll
    for (int t = 0; t < 2; ++t) {
      bf16x8 pa = *(const bf16x8*)&sP[t * 16 + l16][kb + quad * 8];
      oacc[t] = __builtin_amdgcn_mfma_f32_16x16x32_bf16(pa, vb, oacc[t], 0, 0, 0);
    }
  }

#pragma unroll
  for (int t = 0; t < 2; ++t)
#pragma unroll
    for (int r = 0; r < 4; ++r) {
      int q = q0 + t * 16 + quad * 4 + r;
      outb[((size_t)b * NQ + q) * DIM + h * HD + w * 16 + l16] = f2bf(oacc[t][r] * rinv[t][r]);
    }
}

// ---------------- launch ----------------
extern "C" void kernel_launch(void* const* d_in, const int* in_sizes, int n_in,
                              void* d_out, int out_size, void* d_ws, size_t ws_size,
                              hipStream_t stream) {
  const float* x        = (const float*)d_in[0];
  const float* w_qkv    = (const float*)d_in[1];
  const float* b_qkv    = (const float*)d_in[2];
  const float* pool_q_w = (const float*)d_in[3];
  const float* pool_k_w = (const float*)d_in[4];
  const float* pool_v_w = (const float*)d_in[5];
  const float* norm_q_g = (const float*)d_in[6];
  const float* norm_q_b = (const float*)d_in[7];
  const float* norm_k_g = (const float*)d_in[8];
  const float* norm_k_b = (const float*)d_in[9];
  const float* norm_v_g = (const float*)d_in[10];
  const float* norm_v_b = (const float*)d_in[11];
  const float* rel_h    = (const float*)d_in[12];
  const float* rel_w    = (const float*)d_in[13];
  const float* rel_t    = (const float*)d_in[14];
  const float* w_proj   = (const float*)d_in[15];
  const float* b_proj   = (const float*)d_in[16];
  float* out = (float*)d_out;

  const size_t NT  = (size_t)BATCH * NH * NQ * HD;
  const size_t LKT = (size_t)BATCH * NH * LK * HD;
  const size_t LKV = (size_t)BATCH * NH * HD * LKP;   // padded V^T
  const size_t RELN = (size_t)BATCH * NH * NQ * 24;

  ushort* padQ = (ushort*)d_ws;                 // 3*PS bf16
  ushort* qpb  = padQ + 3 * PS;                 // NT bf16
  ushort* kpb  = qpb + NT;                      // LKT bf16
  ushort* vTb  = kpb + LKT;                     // LKV bf16 ([bh][c][kpos], pitch LKP)
  float*  relb = (float*)(vTb + LKV);           // RELN fp32
  ushort* wqkvT = (ushort*)(relb + RELN);
  ushort* wprojT = wqkvT + (size_t)DIM * 3 * DIM;
  float*  wpoolT = (float*)(wprojT + (size_t)DIM * DIM);
  ushort* xb = qpb;                   // overlay: dead before pool writes qpb
  ushort* attn_outb = padQ;           // overlay: padQ dead after pools

  const int M = BATCH * NQ;  // 12544

  zero_kernel<<<2048, 256, 0, stream>>>((uint4*)padQ, (int)(3 * PS * 2 / 16));
  zero_kernel<<<256, 256, 0, stream>>>((uint4*)vTb, (int)(LKV * 2 / 16));
  {
    int n = M * DIM;
    cast_bf16<<<(n / 4 + 255) / 256, 256, 0, stream>>>(x, xb, n);
    transpose_cast<<<dim3(3 * DIM / 32, DIM / 32), 256, 0, stream>>>(w_qkv, wqkvT, DIM, 3 * DIM);
    transpose_cast<<<dim3(DIM / 32, DIM / 32), 256, 0, stream>>>(w_proj, wprojT, DIM, DIM);
    wpool_transpose<<<(3 * 27 * 64 + 255) / 256, 256, 0, stream>>>(
        pool_q_w, pool_k_w, pool_v_w, wpoolT);
  }

  gemm_mfma<1><<<dim3(3 * DIM / 128, M / 128), 256, 0, stream>>>(
      xb, wqkvT, b_qkv, nullptr, padQ, M, 3 * DIM, DIM);

  {
    int wq = BATCH * NH * NQ;
    pool_ln_pad<1, 0><<<(wq + 3) / 4, 256, 0, stream>>>(
        padQ, qpb, wpoolT, norm_q_g, norm_q_b, 14, 14);
    int wk = BATCH * NH * LK;
    pool_ln_pad<2, 0><<<(wk + 3) / 4, 256, 0, stream>>>(
        padQ + PS, kpb, wpoolT + 27 * 64, norm_k_g, norm_k_b, 7, 7);
    pool_ln_pad<2, 1><<<(wk + 3) / 4, 256, 0, stream>>>(
        padQ + 2 * PS, vTb, wpoolT + 2 * 27 * 64, norm_v_g, norm_v_b, 7, 7);
  }

  {
    int total = BATCH * NH * NQ * 22;
    rel_kernel<<<(total + 255) / 256, 256, 0, stream>>>(qpb, rel_h, rel_w, rel_t, relb);
  }

  attn_mfma<<<dim3(NQ / 32, BATCH * NH), 256, 0, stream>>>(qpb, kpb, vTb, relb, attn_outb);

  gemm_mfma<0><<<dim3(DIM / 128, M / 128), 256, 0, stream>>>(
      attn_outb, wprojT, b_proj, out, nullptr, M, DIM, DIM);
}

// Round 3
// 581.596 us; speedup vs baseline: 1.0570x; 1.0523x over previous
//
#include <hip/hip_runtime.h>
#include <hip/hip_bf16.h>

#define BATCH 8
#define NH 12
#define DIM 768
#define HD 64
#define NQ 1568       // 8*14*14
#define TT 8
#define HH_ 14
#define WW_ 14
#define LK 392        // 8*7*7
#define LKP 416       // padded V^T row pitch (13*32), zero tail
#define SCALE 0.125f
#define EPS 1e-5f

// padded pool-input layout: [s][bh][pt 0..9][py 0..15][px 0..15][c]
#define PT 10
#define PPLANE 256            // 16*16
#define PVOL 2560             // PT*PPLANE
#define PS ((size_t)BATCH * NH * PVOL * HD)   // elems per s-third

typedef __bf16 bf16x8 __attribute__((ext_vector_type(8)));
typedef float f32x4 __attribute__((ext_vector_type(4)));

__device__ inline ushort f2bf(float f) {
  __bf16 h = (__bf16)f;              // native v_cvt (RNE), 1 VALU op
  return __builtin_bit_cast(ushort, h);
}
__device__ inline float bf2f(ushort v) { return __uint_as_float((uint)v << 16); }
__device__ inline float bfl(uint u) { return __uint_as_float(u << 16); }
__device__ inline float bfh(uint u) { return __uint_as_float(u & 0xffff0000u); }

// async global->LDS, 16B per lane; LDS dest = wave-uniform base + lane*16
__device__ inline void gload_lds16(const ushort* g, ushort* l) {
  __builtin_amdgcn_global_load_lds(
      (const __attribute__((address_space(1))) void*)g,
      (__attribute__((address_space(3))) void*)l, 16, 0, 0);
}

// ---------------- zero fill ----------------
__global__ __launch_bounds__(256) void zero_kernel(uint4* __restrict__ p, int n16) {
  int i = blockIdx.x * 256 + threadIdx.x;
  int stride = gridDim.x * 256;
  for (; i < n16; i += stride) p[i] = make_uint4(0, 0, 0, 0);
}

// ---------------- cast fp32 -> bf16 ----------------
__global__ __launch_bounds__(256) void cast_bf16(const float* __restrict__ in,
                                                 ushort* __restrict__ outb, int n) {
  int i = (blockIdx.x * blockDim.x + threadIdx.x) * 4;
  if (i >= n) return;
  float4 v = *(const float4*)(in + i);
  ushort4 o = make_ushort4(f2bf(v.x), f2bf(v.y), f2bf(v.z), f2bf(v.w));
  *(ushort4*)(outb + i) = o;
}

// ---------------- transpose + cast: in[R][C] fp32 -> out[C][R] bf16 ----------------
__global__ __launch_bounds__(256) void transpose_cast(const float* __restrict__ in,
                                                      ushort* __restrict__ outb,
                                                      int R, int C) {
  __shared__ float tile[32][33];
  int tx = threadIdx.x & 31, ty = threadIdx.x >> 5;
  int bx = blockIdx.x * 32;
  int by = blockIdx.y * 32;
#pragma unroll
  for (int r = 0; r < 4; ++r)
    tile[ty + r * 8][tx] = in[(size_t)(by + ty + r * 8) * C + bx + tx];
  __syncthreads();
#pragma unroll
  for (int r = 0; r < 4; ++r)
    outb[(size_t)(bx + ty + r * 8) * R + by + tx] = f2bf(tile[tx][ty + r * 8]);
}

// ---------------- pool-weight transpose: [c][27] -> [tap][c], 3 tensors ----------------
__global__ __launch_bounds__(256) void wpool_transpose(const float* __restrict__ wq,
                                                       const float* __restrict__ wk,
                                                       const float* __restrict__ wv,
                                                       float* __restrict__ wT) {
  int i = blockIdx.x * blockDim.x + threadIdx.x;
  if (i >= 3 * 27 * 64) return;
  int s = i / (27 * 64), r = i % (27 * 64), tap = r / 64, c = r % 64;
  const float* src = (s == 0) ? wq : ((s == 1) ? wk : wv);
  wT[i] = src[c * 27 + tap];
}

// ---------------- bf16 MFMA GEMM (m97 structure: global_load_lds, linear LDS) ------
template<int EPI>
__global__ __launch_bounds__(256) void gemm_mfma(const ushort* __restrict__ A,
                                                 const ushort* __restrict__ Bt,
                                                 const float* __restrict__ bias,
                                                 float* __restrict__ outf,
                                                 ushort* __restrict__ outp,
                                                 int M, int N, int K) {
  __shared__ ushort As[128 * 32];   // linear, pitch 32 (required by global_load_lds)
  __shared__ ushort Bs[128 * 32];
  const int tid = threadIdx.x;
  const int wave = tid >> 6, lane = tid & 63;
  const int quad = lane >> 4, l16 = lane & 15;
  const int row0 = blockIdx.y * 128;
  const int col0 = blockIdx.x * 128;
  const int wm = (wave & 1) * 64;
  const int wn = (wave >> 1) * 64;

  f32x4 acc[4][4];
#pragma unroll
  for (int i = 0; i < 4; ++i)
#pragma unroll
    for (int j = 0; j < 4; ++j) acc[i][j] = (f32x4){0.f, 0.f, 0.f, 0.f};

  // staging geometry: wave w issue i covers rows i*64 + w*16 + (lane>>2), col (lane&3)*8
  const int srow = (wave << 4) + (lane >> 2);
  const int scol = (lane & 3) << 3;
  ushort* ldsA = As + wave * 512;      // + i*2048 for second issue
  ushort* ldsB = Bs + wave * 512;
  const ushort* gA = A + (size_t)(row0 + srow) * K + scol;
  const ushort* gB = Bt + (size_t)(col0 + srow) * K + scol;

  for (int k0 = 0; k0 < K; k0 += 32) {
    __syncthreads();                       // prev-tile reads complete
    gload_lds16(gA + k0, ldsA);
    gload_lds16(gA + (size_t)64 * K + k0, ldsA + 2048);
    gload_lds16(gB + k0, ldsB);
    gload_lds16(gB + (size_t)64 * K + k0, ldsB + 2048);
    __syncthreads();                       // drains vmcnt(0): tile visible
    bf16x8 af[4], bfr[4];
#pragma unroll
    for (int i = 0; i < 4; ++i)
      af[i] = *(const bf16x8*)&As[(wm + i * 16 + l16) * 32 + quad * 8];
#pragma unroll
    for (int j = 0; j < 4; ++j)
      bfr[j] = *(const bf16x8*)&Bs[(wn + j * 16 + l16) * 32 + quad * 8];
#pragma unroll
    for (int i = 0; i < 4; ++i)
#pragma unroll
      for (int j = 0; j < 4; ++j)
        acc[i][j] = __builtin_amdgcn_mfma_f32_16x16x32_bf16(af[i], bfr[j], acc[i][j], 0, 0, 0);
  }

#pragma unroll
  for (int i = 0; i < 4; ++i) {
#pragma unroll
    for (int j = 0; j < 4; ++j) {
      int col = col0 + wn + j * 16 + l16;
      float bv = bias[col];
#pragma unroll
      for (int r = 0; r < 4; ++r) {
        int row = row0 + wm + i * 16 + quad * 4 + r;
        float val = acc[i][j][r] + bv;
        if (EPI == 0) {
          outf[(size_t)row * N + col] = val;
        } else {
          int b = row / NQ, nn = row % NQ;
          int s = col / DIM, rr = col % DIM;
          int h = rr >> 6, cc = rr & 63;
          int t = nn / 196, r2 = nn % 196, y = r2 / 14, xx = r2 % 14;
          size_t pidx = (((size_t)s * BATCH * NH + b * NH + h) * PVOL
                         + (t + 1) * PPLANE + (y + 1) * 16 + (xx + 1)) * (size_t)HD + cc;
          outp[pidx] = f2bf(val);
        }
      }
    }
  }
}

// ---------------- padded depthwise pool + LayerNorm(64) -> bf16 ----------------
template<int SW, int VT>
__global__ __launch_bounds__(256) void pool_ln_pad(const ushort* __restrict__ in,
                                                   ushort* __restrict__ out,
                                                   const float* __restrict__ wT,
                                                   const float* __restrict__ g,
                                                   const float* __restrict__ bb,
                                                   int OH, int OW) {
  const int OL = 8 * OH * OW;
  const int wid = (blockIdx.x * blockDim.x + threadIdx.x) >> 6;
  const int lane = threadIdx.x & 63;
  const int total = BATCH * NH * OL;
  if (wid >= total) return;
  const int bh = wid / OL, opos = wid % OL;
  const int ot = opos / (OH * OW);
  const int r = opos % (OH * OW);
  const int oy = r / OW, ox = r % OW;
  const int c = lane;
  const ushort* base = in + ((size_t)bh * PVOL + ot * PPLANE + oy * SW * 16 + ox * SW) * HD + c;

  float v[27], wv[27];
#pragma unroll
  for (int dt = 0; dt < 3; ++dt)
#pragma unroll
    for (int dy = 0; dy < 3; ++dy)
#pragma unroll
      for (int dx = 0; dx < 3; ++dx) {
        int i = (dt * 3 + dy) * 3 + dx;
        v[i] = bf2f(base[(size_t)(dt * PPLANE + dy * 16 + dx) * HD]);
        wv[i] = wT[i * 64 + c];
      }
  float acc = 0.f;
#pragma unroll
  for (int i = 0; i < 27; ++i) acc += v[i] * wv[i];

  float s = acc;
#pragma unroll
  for (int off = 32; off; off >>= 1) s += __shfl_xor(s, off, 64);
  float mean = s * (1.f / 64.f);
  float d = acc - mean;
  float vs = d * d;
#pragma unroll
  for (int off = 32; off; off >>= 1) vs += __shfl_xor(vs, off, 64);
  float inv = rsqrtf(vs * (1.f / 64.f) + EPS);
  float res = d * inv * g[c] + bb[c];
  if (VT == 0) out[(size_t)wid * HD + c] = f2bf(res);
  else         out[((size_t)bh * HD + c) * LKP + opos] = f2bf(res);
}

// ---------------- rel-pos bias precompute (bf16 q) ----------------
__global__ __launch_bounds__(256) void rel_kernel(const ushort* __restrict__ qp,
                                                  const float* __restrict__ Rh,
                                                  const float* __restrict__ Rw,
                                                  const float* __restrict__ Rt,
                                                  float* __restrict__ rel) {
  const int idx = blockIdx.x * blockDim.x + threadIdx.x;
  const int total = BATCH * NH * NQ * 22;
  if (idx >= total) return;
  const int j = idx % 22;
  const int q = idx / 22;
  const int n = q % NQ;
  const int t = n / (HH_ * WW_);
  const int r = n % (HH_ * WW_);
  const int y = r / WW_, x = r % WW_;
  const float* R;
  if (j < 7)       R = Rh + (size_t)(y - 2 * j + 12) * HD;
  else if (j < 14) R = Rw + (size_t)(x - 2 * (j - 7) + 12) * HD;
  else             R = Rt + (size_t)(t - (j - 14) + 7) * HD;
  const ushort* qrow = qp + (size_t)q * HD;
  float acc = 0.f;
#pragma unroll 2
  for (int c = 0; c < HD; c += 8) {
    uint4 qa = *(const uint4*)(qrow + c);
    float4 r0 = *(const float4*)(R + c);
    float4 r1 = *(const float4*)(R + c + 4);
    acc += bfl(qa.x) * r0.x + bfh(qa.x) * r0.y + bfl(qa.y) * r0.z + bfh(qa.y) * r0.w;
    acc += bfl(qa.z) * r1.x + bfh(qa.z) * r1.y + bfl(qa.w) * r1.z + bfh(qa.w) * r1.w;
  }
  rel[(size_t)q * 24 + j] = acc;
}

// ---------------- MFMA attention: 32 queries/block ----
// rel staged TRANSPOSED (same coalesced traffic as the 113us round-0 variant,
// no expansion pass): sRelT[j][q], pitch 36 floats (16B-aligned rows, 4-bank
// row stride). Logits read the 4 q-rows of each fragment with ONE b128 per
// rel term: 42 LDS reads/thread vs 168 scalar b32. kx-term rows 7..13 map to
// disjoint bank quads (stride 4) -> conflict-free; ky/kt terms are <=3
// distinct addresses (broadcast). V loads stay inline in PV (register
// prefetch spilled: round-1 WRITE_SIZE 6x).
__global__ __launch_bounds__(256) void attn_mfma(const ushort* __restrict__ qp,
                                                 const ushort* __restrict__ kp,
                                                 const ushort* __restrict__ vT,
                                                 const float* __restrict__ rel,
                                                 ushort* __restrict__ outb) {
  __shared__ ushort sP[32][424];     // pitch 424: P-read (b128) spreads all banks
  __shared__ float sRelT[24][36];
  __shared__ float sMax[32][4];
  __shared__ float sSum[32][4];
  const int qb = blockIdx.x;        // 0..48
  const int bh = blockIdx.y;        // 0..95
  const int b = bh / NH, h = bh % NH;
  const int tid = threadIdx.x;
  const int w = tid >> 6, lane = tid & 63;
  const int quad = lane >> 4, l16 = lane & 15;
  const int q0 = qb * 32;

  // Q A-fragments direct from global (same for all waves; 4x redundant, tiny)
  const ushort* qbase = qp + ((size_t)bh * NQ + q0) * HD;
  bf16x8 af[2][2];
#pragma unroll
  for (int t = 0; t < 2; ++t) {
    af[t][0] = *(const bf16x8*)(qbase + (size_t)(t * 16 + l16) * HD + quad * 8);
    af[t][1] = *(const bf16x8*)(qbase + (size_t)(t * 16 + l16) * HD + 32 + quad * 8);
  }

  // rel staging, transposed: coalesced global reads (row-major in rel)
  const float* relbase = rel + ((size_t)bh * NQ + q0) * 24;
  for (int e = tid; e < 32 * 22; e += 256) {
    int row = e / 22, j = e % 22;
    sRelT[j][row] = relbase[row * 24 + j];
  }
  // zero P pad cols 400..415
  if (tid < 64) {
    int row = tid >> 1, seg = tid & 1;
    *(uint4*)&sP[row][400 + seg * 8] = make_uint4(0, 0, 0, 0);
  }

  f32x4 acc[7][2];
#pragma unroll
  for (int c = 0; c < 7; ++c)
#pragma unroll
    for (int t = 0; t < 2; ++t) acc[c][t] = (f32x4){0.f, 0.f, 0.f, 0.f};

  // ---- QK^T: wave w owns tiles tg = c*4+w; K B-fragments direct from global ----
  const ushort* kbase = kp + (size_t)bh * LK * HD;
#pragma unroll
  for (int c = 0; c < 7; ++c) {
    int tg = c * 4 + w;
    if (tg < 25) {
      int kg = tg * 16 + l16;
      int kgc = kg < LK ? kg : (LK - 1);   // clamp; masked below
      const ushort* krow = kbase + (size_t)kgc * HD;
      bf16x8 b0 = *(const bf16x8*)(krow + quad * 8);
      bf16x8 b1 = *(const bf16x8*)(krow + 32 + quad * 8);
#pragma unroll
      for (int t = 0; t < 2; ++t) {
        acc[c][t] = __builtin_amdgcn_mfma_f32_16x16x32_bf16(af[t][0], b0, acc[c][t], 0, 0, 0);
        acc[c][t] = __builtin_amdgcn_mfma_f32_16x16x32_bf16(af[t][1], b1, acc[c][t], 0, 0, 0);
      }
    }
  }
  __syncthreads();   // barrier 1: sRelT (and sP pad) visible

  // ---- logits: scale + rel bias, one b128 per term per (c,t) ----
#pragma unroll
  for (int c = 0; c < 7; ++c) {
    int tg = c * 4 + w;
    int kg = tg * 16 + l16;
    if (tg < 25) {
      int kgc = kg < LK ? kg : 0;
      bool ok = kg < LK;
      int kt = kgc / 49, kyx = kgc % 49, ky = kyx / 7, kx = kyx % 7;
#pragma unroll
      for (int t = 0; t < 2; ++t) {
        f32x4 bh4 = *(const f32x4*)&sRelT[ky][t * 16 + quad * 4];
        f32x4 bw4 = *(const f32x4*)&sRelT[7 + kx][t * 16 + quad * 4];
        f32x4 bt4 = *(const f32x4*)&sRelT[14 + kt][t * 16 + quad * 4];
#pragma unroll
        for (int r = 0; r < 4; ++r)
          acc[c][t][r] = ok ? (acc[c][t][r] * SCALE + bh4[r] + bw4[r] + bt4[r]) : -1e30f;
      }
    } else {
#pragma unroll
      for (int t = 0; t < 2; ++t)
#pragma unroll
        for (int r = 0; r < 4; ++r) acc[c][t][r] = -1e30f;
    }
  }

  // ---- row max: reduce over l16, exchange across waves ----
  float pmax[2][4];
#pragma unroll
  for (int t = 0; t < 2; ++t)
#pragma unroll
    for (int r = 0; r < 4; ++r) {
      float m = acc[0][t][r];
#pragma unroll
      for (int c = 1; c < 7; ++c) m = fmaxf(m, acc[c][t][r]);
#pragma unroll
      for (int off = 1; off < 16; off <<= 1) m = fmaxf(m, __shfl_xor(m, off, 64));
      pmax[t][r] = m;
    }
  if (l16 == 0) {
#pragma unroll
    for (int t = 0; t < 2; ++t)
#pragma unroll
      for (int r = 0; r < 4; ++r) sMax[t * 16 + quad * 4 + r][w] = pmax[t][r];
  }
  __syncthreads();   // barrier 2

  float M[2][4];
#pragma unroll
  for (int t = 0; t < 2; ++t)
#pragma unroll
    for (int r = 0; r < 4; ++r) {
      float4 mm = *(float4*)&sMax[t * 16 + quad * 4 + r][0];
      M[t][r] = fmaxf(fmaxf(mm.x, mm.y), fmaxf(mm.z, mm.w));
    }

  // ---- exp, partial sums, P write ----
  float psum[2][4];
#pragma unroll
  for (int t = 0; t < 2; ++t)
#pragma unroll
    for (int r = 0; r < 4; ++r) psum[t][r] = 0.f;
#pragma unroll
  for (int c = 0; c < 7; ++c) {
#pragma unroll
    for (int t = 0; t < 2; ++t)
#pragma unroll
      for (int r = 0; r < 4; ++r) {
        float e = __expf(acc[c][t][r] - M[t][r]);
        acc[c][t][r] = e;
        psum[t][r] += e;
      }
  }
#pragma unroll
  for (int t = 0; t < 2; ++t)
#pragma unroll
    for (int r = 0; r < 4; ++r) {
      float s = psum[t][r];
#pragma unroll
      for (int off = 1; off < 16; off <<= 1) s += __shfl_xor(s, off, 64);
      psum[t][r] = s;
    }
  if (l16 == 0) {
#pragma unroll
    for (int t = 0; t < 2; ++t)
#pragma unroll
      for (int r = 0; r < 4; ++r) sSum[t * 16 + quad * 4 + r][w] = psum[t][r];
  }
#pragma unroll
  for (int c = 0; c < 7; ++c) {
    int tg = c * 4 + w;
    if (tg < 25) {
      int kg = tg * 16 + l16;
#pragma unroll
      for (int t = 0; t < 2; ++t)
#pragma unroll
        for (int r = 0; r < 4; ++r)
          sP[t * 16 + quad * 4 + r][kg] = f2bf(acc[c][t][r]);
    }
  }
  __syncthreads();   // barrier 3

  float rinv[2][4];
#pragma unroll
  for (int t = 0; t < 2; ++t)
#pragma unroll
    for (int r = 0; r < 4; ++r) {
      float4 ss = *(float4*)&sSum[t * 16 + quad * 4 + r][0];
      rinv[t][r] = 1.f / (ss.x + ss.y + ss.z + ss.w);
    }

  // ---- PV: V^T B-fragments direct from global (padded pitch LKP, zero tail) ----
  f32x4 oacc[2];
  oacc[0] = (f32x4){0.f, 0.f, 0.f, 0.f};
  oacc[1] = (f32x4){0.f, 0.f, 0.f, 0.f};
  const ushort* vrow = vT + ((size_t)bh * HD + w * 16 + l16) * LKP;
#pragma unroll
  for (int s = 0; s < 13; ++s) {
    int kb = s * 32;
    bf16x8 vb = *(const bf16x8*)(vrow + kb + quad * 8);
#pragma unroll
    for (int t = 0; t < 2; ++t) {
      bf16x8 pa = *(const bf16x8*)&sP[t * 16 + l16][kb + quad * 8];
      oacc[t] = __builtin_amdgcn_mfma_f32_16x16x32_bf16(pa, vb, oacc[t], 0, 0, 0);
    }
  }

#pragma unroll
  for (int t = 0; t < 2; ++t)
#pragma unroll
    for (int r = 0; r < 4; ++r) {
      int q = q0 + t * 16 + quad * 4 + r;
      outb[((size_t)b * NQ + q) * DIM + h * HD + w * 16 + l16] = f2bf(oacc[t][r] * rinv[t][r]);
    }
}

// ---------------- launch ----------------
extern "C" void kernel_launch(void* const* d_in, const int* in_sizes, int n_in,
                              void* d_out, int out_size, void* d_ws, size_t ws_size,
                              hipStream_t stream) {
  const float* x        = (const float*)d_in[0];
  const float* w_qkv    = (const float*)d_in[1];
  const float* b_qkv    = (const float*)d_in[2];
  const float* pool_q_w = (const float*)d_in[3];
  const float* pool_k_w = (const float*)d_in[4];
  const float* pool_v_w = (const float*)d_in[5];
  const float* norm_q_g = (const float*)d_in[6];
  const float* norm_q_b = (const float*)d_in[7];
  const float* norm_k_g = (const float*)d_in[8];
  const float* norm_k_b = (const float*)d_in[9];
  const float* norm_v_g = (const float*)d_in[10];
  const float* norm_v_b = (const float*)d_in[11];
  const float* rel_h    = (const float*)d_in[12];
  const float* rel_w    = (const float*)d_in[13];
  const float* rel_t    = (const float*)d_in[14];
  const float* w_proj   = (const float*)d_in[15];
  const float* b_proj   = (const float*)d_in[16];
  float* out = (float*)d_out;

  const size_t NT  = (size_t)BATCH * NH * NQ * HD;
  const size_t LKT = (size_t)BATCH * NH * LK * HD;
  const size_t LKV = (size_t)BATCH * NH * HD * LKP;   // padded V^T
  const size_t RELN = (size_t)BATCH * NH * NQ * 24;

  ushort* padQ = (ushort*)d_ws;                 // 3*PS bf16
  ushort* qpb  = padQ + 3 * PS;                 // NT bf16
  ushort* kpb  = qpb + NT;                      // LKT bf16
  ushort* vTb  = kpb + LKT;                     // LKV bf16 ([bh][c][kpos], pitch LKP)
  float*  relb = (float*)(vTb + LKV);           // RELN fp32
  ushort* wqkvT = (ushort*)(relb + RELN);
  ushort* wprojT = wqkvT + (size_t)DIM * 3 * DIM;
  float*  wpoolT = (float*)(wprojT + (size_t)DIM * DIM);
  ushort* xb = qpb;                   // overlay: dead before pool writes qpb
  ushort* attn_outb = padQ;           // overlay: padQ dead after pools

  const int M = BATCH * NQ;  // 12544

  zero_kernel<<<2048, 256, 0, stream>>>((uint4*)padQ, (int)(3 * PS * 2 / 16));
  zero_kernel<<<256, 256, 0, stream>>>((uint4*)vTb, (int)(LKV * 2 / 16));
  {
    int n = M * DIM;
    cast_bf16<<<(n / 4 + 255) / 256, 256, 0, stream>>>(x, xb, n);
    transpose_cast<<<dim3(3 * DIM / 32, DIM / 32), 256, 0, stream>>>(w_qkv, wqkvT, DIM, 3 * DIM);
    transpose_cast<<<dim3(DIM / 32, DIM / 32), 256, 0, stream>>>(w_proj, wprojT, DIM, DIM);
    wpool_transpose<<<(3 * 27 * 64 + 255) / 256, 256, 0, stream>>>(
        pool_q_w, pool_k_w, pool_v_w, wpoolT);
  }

  gemm_mfma<1><<<dim3(3 * DIM / 128, M / 128), 256, 0, stream>>>(
      xb, wqkvT, b_qkv, nullptr, padQ, M, 3 * DIM, DIM);

  {
    int wq = BATCH * NH * NQ;
    pool_ln_pad<1, 0><<<(wq + 3) / 4, 256, 0, stream>>>(
        padQ, qpb, wpoolT, norm_q_g, norm_q_b, 14, 14);
    int wk = BATCH * NH * LK;
    pool_ln_pad<2, 0><<<(wk + 3) / 4, 256, 0, stream>>>(
        padQ + PS, kpb, wpoolT + 27 * 64, norm_k_g, norm_k_b, 7, 7);
    pool_ln_pad<2, 1><<<(wk + 3) / 4, 256, 0, stream>>>(
        padQ + 2 * PS, vTb, wpoolT + 2 * 27 * 64, norm_v_g, norm_v_b, 7, 7);
  }

  {
    int total = BATCH * NH * NQ * 22;
    rel_kernel<<<(total + 255) / 256, 256, 0, stream>>>(qpb, rel_h, rel_w, rel_t, relb);
  }

  attn_mfma<<<dim3(NQ / 32, BATCH * NH), 256, 0, stream>>>(qpb, kpb, vTb, relb, attn_outb);

  gemm_mfma<0><<<dim3(DIM / 128, M / 128), 256, 0, stream>>>(
      attn_outb, wprojT, b_proj, out, nullptr, M, DIM, DIM);
}

// Round 4
// 496.913 us; speedup vs baseline: 1.2372x; 1.1704x over previous
//
#include <hip/hip_runtime.h>
#include <hip/hip_bf16.h>

#define BATCH 8
#define NH 12
#define DIM 768
#define HD 64
#define NQ 1568       // 8*14*14
#define TT 8
#define HH_ 14
#define WW_ 14
#define LK 392        // 8*7*7
#define LKP 416       // padded V^T row pitch (13*32), zero tail
#define SCALE 0.125f
#define EPS 1e-5f

// padded pool-input layout: [s][bh][pt 0..9][py 0..15][px 0..15][c]
#define PT 10
#define PPLANE 256            // 16*16
#define PVOL 2560             // PT*PPLANE
#define PS ((size_t)BATCH * NH * PVOL * HD)   // elems per s-third

typedef __bf16 bf16x8 __attribute__((ext_vector_type(8)));
typedef float f32x4 __attribute__((ext_vector_type(4)));

__device__ inline ushort f2bf(float f) {
  __bf16 h = (__bf16)f;              // native v_cvt (RNE), 1 VALU op
  return __builtin_bit_cast(ushort, h);
}
__device__ inline float bf2f(ushort v) { return __uint_as_float((uint)v << 16); }
__device__ inline float bfl(uint u) { return __uint_as_float(u << 16); }
__device__ inline float bfh(uint u) { return __uint_as_float(u & 0xffff0000u); }

// async global->LDS, 16B per lane; LDS dest = wave-uniform base + lane*16
__device__ inline void gload_lds16(const ushort* g, ushort* l) {
  __builtin_amdgcn_global_load_lds(
      (const __attribute__((address_space(1))) void*)g,
      (__attribute__((address_space(3))) void*)l, 16, 0, 0);
}

// ---------------- zero fill ----------------
__global__ __launch_bounds__(256) void zero_kernel(uint4* __restrict__ p, int n16) {
  int i = blockIdx.x * 256 + threadIdx.x;
  int stride = gridDim.x * 256;
  for (; i < n16; i += stride) p[i] = make_uint4(0, 0, 0, 0);
}

// ---------------- cast fp32 -> bf16 ----------------
__global__ __launch_bounds__(256) void cast_bf16(const float* __restrict__ in,
                                                 ushort* __restrict__ outb, int n) {
  int i = (blockIdx.x * blockDim.x + threadIdx.x) * 4;
  if (i >= n) return;
  float4 v = *(const float4*)(in + i);
  ushort4 o = make_ushort4(f2bf(v.x), f2bf(v.y), f2bf(v.z), f2bf(v.w));
  *(ushort4*)(outb + i) = o;
}

// ---------------- transpose + cast: in[R][C] fp32 -> out[C][R] bf16 ----------------
__global__ __launch_bounds__(256) void transpose_cast(const float* __restrict__ in,
                                                      ushort* __restrict__ outb,
                                                      int R, int C) {
  __shared__ float tile[32][33];
  int tx = threadIdx.x & 31, ty = threadIdx.x >> 5;
  int bx = blockIdx.x * 32;
  int by = blockIdx.y * 32;
#pragma unroll
  for (int r = 0; r < 4; ++r)
    tile[ty + r * 8][tx] = in[(size_t)(by + ty + r * 8) * C + bx + tx];
  __syncthreads();
#pragma unroll
  for (int r = 0; r < 4; ++r)
    outb[(size_t)(bx + ty + r * 8) * R + by + tx] = f2bf(tile[tx][ty + r * 8]);
}

// ---------------- pool-weight transpose: [c][27] -> [tap][c], 3 tensors ----------------
__global__ __launch_bounds__(256) void wpool_transpose(const float* __restrict__ wq,
                                                       const float* __restrict__ wk,
                                                       const float* __restrict__ wv,
                                                       float* __restrict__ wT) {
  int i = blockIdx.x * blockDim.x + threadIdx.x;
  if (i >= 3 * 27 * 64) return;
  int s = i / (27 * 64), r = i % (27 * 64), tap = r / 64, c = r % 64;
  const float* src = (s == 0) ? wq : ((s == 1) ? wk : wv);
  wT[i] = src[c * 27 + tap];
}

// ---------------- bf16 MFMA GEMM (m97 structure: global_load_lds, linear LDS) ------
template<int EPI>
__global__ __launch_bounds__(256) void gemm_mfma(const ushort* __restrict__ A,
                                                 const ushort* __restrict__ Bt,
                                                 const float* __restrict__ bias,
                                                 float* __restrict__ outf,
                                                 ushort* __restrict__ outp,
                                                 int M, int N, int K) {
  __shared__ ushort As[128 * 32];   // linear, pitch 32 (required by global_load_lds)
  __shared__ ushort Bs[128 * 32];
  const int tid = threadIdx.x;
  const int wave = tid >> 6, lane = tid & 63;
  const int quad = lane >> 4, l16 = lane & 15;
  const int row0 = blockIdx.y * 128;
  const int col0 = blockIdx.x * 128;
  const int wm = (wave & 1) * 64;
  const int wn = (wave >> 1) * 64;

  f32x4 acc[4][4];
#pragma unroll
  for (int i = 0; i < 4; ++i)
#pragma unroll
    for (int j = 0; j < 4; ++j) acc[i][j] = (f32x4){0.f, 0.f, 0.f, 0.f};

  // staging geometry: wave w issue i covers rows i*64 + w*16 + (lane>>2), col (lane&3)*8
  const int srow = (wave << 4) + (lane >> 2);
  const int scol = (lane & 3) << 3;
  ushort* ldsA = As + wave * 512;      // + i*2048 for second issue
  ushort* ldsB = Bs + wave * 512;
  const ushort* gA = A + (size_t)(row0 + srow) * K + scol;
  const ushort* gB = Bt + (size_t)(col0 + srow) * K + scol;

  for (int k0 = 0; k0 < K; k0 += 32) {
    __syncthreads();                       // prev-tile reads complete
    gload_lds16(gA + k0, ldsA);
    gload_lds16(gA + (size_t)64 * K + k0, ldsA + 2048);
    gload_lds16(gB + k0, ldsB);
    gload_lds16(gB + (size_t)64 * K + k0, ldsB + 2048);
    __syncthreads();                       // drains vmcnt(0): tile visible
    bf16x8 af[4], bfr[4];
#pragma unroll
    for (int i = 0; i < 4; ++i)
      af[i] = *(const bf16x8*)&As[(wm + i * 16 + l16) * 32 + quad * 8];
#pragma unroll
    for (int j = 0; j < 4; ++j)
      bfr[j] = *(const bf16x8*)&Bs[(wn + j * 16 + l16) * 32 + quad * 8];
#pragma unroll
    for (int i = 0; i < 4; ++i)
#pragma unroll
      for (int j = 0; j < 4; ++j)
        acc[i][j] = __builtin_amdgcn_mfma_f32_16x16x32_bf16(af[i], bfr[j], acc[i][j], 0, 0, 0);
  }

#pragma unroll
  for (int i = 0; i < 4; ++i) {
#pragma unroll
    for (int j = 0; j < 4; ++j) {
      int col = col0 + wn + j * 16 + l16;
      float bv = bias[col];
#pragma unroll
      for (int r = 0; r < 4; ++r) {
        int row = row0 + wm + i * 16 + quad * 4 + r;
        float val = acc[i][j][r] + bv;
        if (EPI == 0) {
          outf[(size_t)row * N + col] = val;
        } else {
          int b = row / NQ, nn = row % NQ;
          int s = col / DIM, rr = col % DIM;
          int h = rr >> 6, cc = rr & 63;
          int t = nn / 196, r2 = nn % 196, y = r2 / 14, xx = r2 % 14;
          size_t pidx = (((size_t)s * BATCH * NH + b * NH + h) * PVOL
                         + (t + 1) * PPLANE + (y + 1) * 16 + (xx + 1)) * (size_t)HD + cc;
          outp[pidx] = f2bf(val);
        }
      }
    }
  }
}

// ---------------- padded depthwise pool + LayerNorm(64) -> bf16 ----------------
template<int SW, int VT>
__global__ __launch_bounds__(256) void pool_ln_pad(const ushort* __restrict__ in,
                                                   ushort* __restrict__ out,
                                                   const float* __restrict__ wT,
                                                   const float* __restrict__ g,
                                                   const float* __restrict__ bb,
                                                   int OH, int OW) {
  const int OL = 8 * OH * OW;
  const int wid = (blockIdx.x * blockDim.x + threadIdx.x) >> 6;
  const int lane = threadIdx.x & 63;
  const int total = BATCH * NH * OL;
  if (wid >= total) return;
  const int bh = wid / OL, opos = wid % OL;
  const int ot = opos / (OH * OW);
  const int r = opos % (OH * OW);
  const int oy = r / OW, ox = r % OW;
  const int c = lane;
  const ushort* base = in + ((size_t)bh * PVOL + ot * PPLANE + oy * SW * 16 + ox * SW) * HD + c;

  float v[27], wv[27];
#pragma unroll
  for (int dt = 0; dt < 3; ++dt)
#pragma unroll
    for (int dy = 0; dy < 3; ++dy)
#pragma unroll
      for (int dx = 0; dx < 3; ++dx) {
        int i = (dt * 3 + dy) * 3 + dx;
        v[i] = bf2f(base[(size_t)(dt * PPLANE + dy * 16 + dx) * HD]);
        wv[i] = wT[i * 64 + c];
      }
  float acc = 0.f;
#pragma unroll
  for (int i = 0; i < 27; ++i) acc += v[i] * wv[i];

  float s = acc;
#pragma unroll
  for (int off = 32; off; off >>= 1) s += __shfl_xor(s, off, 64);
  float mean = s * (1.f / 64.f);
  float d = acc - mean;
  float vs = d * d;
#pragma unroll
  for (int off = 32; off; off >>= 1) vs += __shfl_xor(vs, off, 64);
  float inv = rsqrtf(vs * (1.f / 64.f) + EPS);
  float res = d * inv * g[c] + bb[c];
  if (VT == 0) out[(size_t)wid * HD + c] = f2bf(res);
  else         out[((size_t)bh * HD + c) * LKP + opos] = f2bf(res);
}

// ---------------- rel-pos bias via MFMA GEMM ----------------
// rel67 = Q[150528x64] . Rcat^T, Rcat = concat(Rh 26, Rw 26, Rt 15) rows x 64.
// Epilogue inverts the index map and scatters the 22 valid slots per q-row
// into rel[q*24+j] (identical layout to the old scalar kernel).
__global__ __launch_bounds__(256) void rel_gemm(const ushort* __restrict__ qp,
                                                const float* __restrict__ Rh,
                                                const float* __restrict__ Rw,
                                                const float* __restrict__ Rt,
                                                float* __restrict__ rel) {
  __shared__ ushort sR[80 * 72];   // [n][k] bf16, pitch 72 (row stride 4 banks mod 32)
  const int tid = threadIdx.x;
  const int wave = tid >> 6, lane = tid & 63;
  const int quad = lane >> 4, l16 = lane & 15;
  const int row0 = blockIdx.x * 128;

  // stage Rcat -> LDS bf16 (L2-hot, 17KB fp32)
  for (int e = tid; e < 80 * 64; e += 256) {
    int n = e >> 6, k = e & 63;
    float v;
    if (n < 26)      v = Rh[n * 64 + k];
    else if (n < 52) v = Rw[(n - 26) * 64 + k];
    else if (n < 67) v = Rt[(n - 52) * 64 + k];
    else             v = 0.f;
    sR[n * 72 + k] = f2bf(v);
  }
  __syncthreads();

  // A fragments: wave owns rows rbase..rbase+31 (2 m-frags), K=64 (2 k-steps)
  const int rbase = row0 + wave * 32;
  bf16x8 af[2][2];
#pragma unroll
  for (int m = 0; m < 2; ++m)
#pragma unroll
    for (int ks = 0; ks < 2; ++ks)
      af[m][ks] = *(const bf16x8*)(qp + (size_t)(rbase + m * 16 + l16) * HD + ks * 32 + quad * 8);

  f32x4 acc[2][5];
#pragma unroll
  for (int m = 0; m < 2; ++m)
#pragma unroll
    for (int n = 0; n < 5; ++n) acc[m][n] = (f32x4){0.f, 0.f, 0.f, 0.f};

#pragma unroll
  for (int n = 0; n < 5; ++n) {
#pragma unroll
    for (int ks = 0; ks < 2; ++ks) {
      bf16x8 bfr = *(const bf16x8*)&sR[(n * 16 + l16) * 72 + ks * 32 + quad * 8];
#pragma unroll
      for (int m = 0; m < 2; ++m)
        acc[m][n] = __builtin_amdgcn_mfma_f32_16x16x32_bf16(af[m][ks], bfr, acc[m][n], 0, 0, 0);
    }
  }

  // epilogue: C element (row = rbase + m*16 + quad*4 + r, col c = n*16 + l16)
#pragma unroll
  for (int m = 0; m < 2; ++m) {
#pragma unroll
    for (int r = 0; r < 4; ++r) {
      int q = rbase + m * 16 + quad * 4 + r;
      int n_ = q % NQ;
      int t = n_ / 196, r2 = n_ % 196, y = r2 / 14, x = r2 % 14;
      float* relq = rel + (size_t)q * 24;
#pragma unroll
      for (int n = 0; n < 5; ++n) {
        int c = n * 16 + l16;
        float val = acc[m][n][r];
        if (c < 26) {
          int dy = y + 12 - c;
          if (dy >= 0 && dy <= 12 && (dy & 1) == 0) relq[dy >> 1] = val;
        } else if (c < 52) {
          int dx = x + 12 - (c - 26);
          if (dx >= 0 && dx <= 12 && (dx & 1) == 0) relq[7 + (dx >> 1)] = val;
        } else if (c < 67) {
          int dt = t + 7 - (c - 52);
          if (dt >= 0 && dt <= 7) relq[14 + dt] = val;
        }
      }
    }
  }
}

// ---------------- MFMA attention: 32 queries/block ----
// rel staged TRANSPOSED: sRelT[j][q], pitch 36 floats. Logits read the 4
// q-rows of each fragment with ONE b128 per rel term. V loads inline in PV.
__global__ __launch_bounds__(256) void attn_mfma(const ushort* __restrict__ qp,
                                                 const ushort* __restrict__ kp,
                                                 const ushort* __restrict__ vT,
                                                 const float* __restrict__ rel,
                                                 ushort* __restrict__ outb) {
  __shared__ ushort sP[32][424];     // pitch 424: P-read (b128) spreads all banks
  __shared__ float sRelT[24][36];
  __shared__ float sMax[32][4];
  __shared__ float sSum[32][4];
  const int qb = blockIdx.x;        // 0..48
  const int bh = blockIdx.y;        // 0..95
  const int b = bh / NH, h = bh % NH;
  const int tid = threadIdx.x;
  const int w = tid >> 6, lane = tid & 63;
  const int quad = lane >> 4, l16 = lane & 15;
  const int q0 = qb * 32;

  // Q A-fragments direct from global (same for all waves; 4x redundant, tiny)
  const ushort* qbase = qp + ((size_t)bh * NQ + q0) * HD;
  bf16x8 af[2][2];
#pragma unroll
  for (int t = 0; t < 2; ++t) {
    af[t][0] = *(const bf16x8*)(qbase + (size_t)(t * 16 + l16) * HD + quad * 8);
    af[t][1] = *(const bf16x8*)(qbase + (size_t)(t * 16 + l16) * HD + 32 + quad * 8);
  }

  // rel staging, transposed: coalesced global reads (row-major in rel)
  const float* relbase = rel + ((size_t)bh * NQ + q0) * 24;
  for (int e = tid; e < 32 * 22; e += 256) {
    int row = e / 22, j = e % 22;
    sRelT[j][row] = relbase[row * 24 + j];
  }
  // zero P pad cols 400..415
  if (tid < 64) {
    int row = tid >> 1, seg = tid & 1;
    *(uint4*)&sP[row][400 + seg * 8] = make_uint4(0, 0, 0, 0);
  }

  f32x4 acc[7][2];
#pragma unroll
  for (int c = 0; c < 7; ++c)
#pragma unroll
    for (int t = 0; t < 2; ++t) acc[c][t] = (f32x4){0.f, 0.f, 0.f, 0.f};

  // ---- QK^T: wave w owns tiles tg = c*4+w; K B-fragments direct from global ----
  const ushort* kbase = kp + (size_t)bh * LK * HD;
#pragma unroll
  for (int c = 0; c < 7; ++c) {
    int tg = c * 4 + w;
    if (tg < 25) {
      int kg = tg * 16 + l16;
      int kgc = kg < LK ? kg : (LK - 1);   // clamp; masked below
      const ushort* krow = kbase + (size_t)kgc * HD;
      bf16x8 b0 = *(const bf16x8*)(krow + quad * 8);
      bf16x8 b1 = *(const bf16x8*)(krow + 32 + quad * 8);
#pragma unroll
      for (int t = 0; t < 2; ++t) {
        acc[c][t] = __builtin_amdgcn_mfma_f32_16x16x32_bf16(af[t][0], b0, acc[c][t], 0, 0, 0);
        acc[c][t] = __builtin_amdgcn_mfma_f32_16x16x32_bf16(af[t][1], b1, acc[c][t], 0, 0, 0);
      }
    }
  }
  __syncthreads();   // barrier 1: sRelT (and sP pad) visible

  // ---- logits: scale + rel bias, one b128 per term per (c,t) ----
#pragma unroll
  for (int c = 0; c < 7; ++c) {
    int tg = c * 4 + w;
    int kg = tg * 16 + l16;
    if (tg < 25) {
      int kgc = kg < LK ? kg : 0;
      bool ok = kg < LK;
      int kt = kgc / 49, kyx = kgc % 49, ky = kyx / 7, kx = kyx % 7;
#pragma unroll
      for (int t = 0; t < 2; ++t) {
        f32x4 bh4 = *(const f32x4*)&sRelT[ky][t * 16 + quad * 4];
        f32x4 bw4 = *(const f32x4*)&sRelT[7 + kx][t * 16 + quad * 4];
        f32x4 bt4 = *(const f32x4*)&sRelT[14 + kt][t * 16 + quad * 4];
#pragma unroll
        for (int r = 0; r < 4; ++r)
          acc[c][t][r] = ok ? (acc[c][t][r] * SCALE + bh4[r] + bw4[r] + bt4[r]) : -1e30f;
      }
    } else {
#pragma unroll
      for (int t = 0; t < 2; ++t)
#pragma unroll
        for (int r = 0; r < 4; ++r) acc[c][t][r] = -1e30f;
    }
  }

  // ---- row max: reduce over l16, exchange across waves ----
  float pmax[2][4];
#pragma unroll
  for (int t = 0; t < 2; ++t)
#pragma unroll
    for (int r = 0; r < 4; ++r) {
      float m = acc[0][t][r];
#pragma unroll
      for (int c = 1; c < 7; ++c) m = fmaxf(m, acc[c][t][r]);
#pragma unroll
      for (int off = 1; off < 16; off <<= 1) m = fmaxf(m, __shfl_xor(m, off, 64));
      pmax[t][r] = m;
    }
  if (l16 == 0) {
#pragma unroll
    for (int t = 0; t < 2; ++t)
#pragma unroll
      for (int r = 0; r < 4; ++r) sMax[t * 16 + quad * 4 + r][w] = pmax[t][r];
  }
  __syncthreads();   // barrier 2

  float M[2][4];
#pragma unroll
  for (int t = 0; t < 2; ++t)
#pragma unroll
    for (int r = 0; r < 4; ++r) {
      float4 mm = *(float4*)&sMax[t * 16 + quad * 4 + r][0];
      M[t][r] = fmaxf(fmaxf(mm.x, mm.y), fmaxf(mm.z, mm.w));
    }

  // ---- exp, partial sums, P write ----
  float psum[2][4];
#pragma unroll
  for (int t = 0; t < 2; ++t)
#pragma unroll
    for (int r = 0; r < 4; ++r) psum[t][r] = 0.f;
#pragma unroll
  for (int c = 0; c < 7; ++c) {
#pragma unroll
    for (int t = 0; t < 2; ++t)
#pragma unroll
      for (int r = 0; r < 4; ++r) {
        float e = __expf(acc[c][t][r] - M[t][r]);
        acc[c][t][r] = e;
        psum[t][r] += e;
      }
  }
#pragma unroll
  for (int t = 0; t < 2; ++t)
#pragma unroll
    for (int r = 0; r < 4; ++r) {
      float s = psum[t][r];
#pragma unroll
      for (int off = 1; off < 16; off <<= 1) s += __shfl_xor(s, off, 64);
      psum[t][r] = s;
    }
  if (l16 == 0) {
#pragma unroll
    for (int t = 0; t < 2; ++t)
#pragma unroll
      for (int r = 0; r < 4; ++r) sSum[t * 16 + quad * 4 + r][w] = psum[t][r];
  }
#pragma unroll
  for (int c = 0; c < 7; ++c) {
    int tg = c * 4 + w;
    if (tg < 25) {
      int kg = tg * 16 + l16;
#pragma unroll
      for (int t = 0; t < 2; ++t)
#pragma unroll
        for (int r = 0; r < 4; ++r)
          sP[t * 16 + quad * 4 + r][kg] = f2bf(acc[c][t][r]);
    }
  }
  __syncthreads();   // barrier 3

  float rinv[2][4];
#pragma unroll
  for (int t = 0; t < 2; ++t)
#pragma unroll
    for (int r = 0; r < 4; ++r) {
      float4 ss = *(float4*)&sSum[t * 16 + quad * 4 + r][0];
      rinv[t][r] = 1.f / (ss.x + ss.y + ss.z + ss.w);
    }

  // ---- PV: V^T B-fragments direct from global (padded pitch LKP, zero tail) ----
  f32x4 oacc[2];
  oacc[0] = (f32x4){0.f, 0.f, 0.f, 0.f};
  oacc[1] = (f32x4){0.f, 0.f, 0.f, 0.f};
  const ushort* vrow = vT + ((size_t)bh * HD + w * 16 + l16) * LKP;
#pragma unroll
  for (int s = 0; s < 13; ++s) {
    int kb = s * 32;
    bf16x8 vb = *(const bf16x8*)(vrow + kb + quad * 8);
#pragma unroll
    for (int t = 0; t < 2; ++t) {
      bf16x8 pa = *(const bf16x8*)&sP[t * 16 + l16][kb + quad * 8];
      oacc[t] = __builtin_amdgcn_mfma_f32_16x16x32_bf16(pa, vb, oacc[t], 0, 0, 0);
    }
  }

#pragma unroll
  for (int t = 0; t < 2; ++t)
#pragma unroll
    for (int r = 0; r < 4; ++r) {
      int q = q0 + t * 16 + quad * 4 + r;
      outb[((size_t)b * NQ + q) * DIM + h * HD + w * 16 + l16] = f2bf(oacc[t][r] * rinv[t][r]);
    }
}

// ---------------- launch ----------------
extern "C" void kernel_launch(void* const* d_in, const int* in_sizes, int n_in,
                              void* d_out, int out_size, void* d_ws, size_t ws_size,
                              hipStream_t stream) {
  const float* x        = (const float*)d_in[0];
  const float* w_qkv    = (const float*)d_in[1];
  const float* b_qkv    = (const float*)d_in[2];
  const float* pool_q_w = (const float*)d_in[3];
  const float* pool_k_w = (const float*)d_in[4];
  const float* pool_v_w = (const float*)d_in[5];
  const float* norm_q_g = (const float*)d_in[6];
  const float* norm_q_b = (const float*)d_in[7];
  const float* norm_k_g = (const float*)d_in[8];
  const float* norm_k_b = (const float*)d_in[9];
  const float* norm_v_g = (const float*)d_in[10];
  const float* norm_v_b = (const float*)d_in[11];
  const float* rel_h    = (const float*)d_in[12];
  const float* rel_w    = (const float*)d_in[13];
  const float* rel_t    = (const float*)d_in[14];
  const float* w_proj   = (const float*)d_in[15];
  const float* b_proj   = (const float*)d_in[16];
  float* out = (float*)d_out;

  const size_t NT  = (size_t)BATCH * NH * NQ * HD;
  const size_t LKT = (size_t)BATCH * NH * LK * HD;
  const size_t LKV = (size_t)BATCH * NH * HD * LKP;   // padded V^T
  const size_t RELN = (size_t)BATCH * NH * NQ * 24;

  ushort* padQ = (ushort*)d_ws;                 // 3*PS bf16
  ushort* qpb  = padQ + 3 * PS;                 // NT bf16
  ushort* kpb  = qpb + NT;                      // LKT bf16
  ushort* vTb  = kpb + LKT;                     // LKV bf16 ([bh][c][kpos], pitch LKP)
  float*  relb = (float*)(vTb + LKV);           // RELN fp32
  ushort* wqkvT = (ushort*)(relb + RELN);
  ushort* wprojT = wqkvT + (size_t)DIM * 3 * DIM;
  float*  wpoolT = (float*)(wprojT + (size_t)DIM * DIM);
  ushort* xb = qpb;                   // overlay: dead before pool writes qpb
  ushort* attn_outb = padQ;           // overlay: padQ dead after pools

  const int M = BATCH * NQ;  // 12544

  zero_kernel<<<2048, 256, 0, stream>>>((uint4*)padQ, (int)(3 * PS * 2 / 16));
  zero_kernel<<<256, 256, 0, stream>>>((uint4*)vTb, (int)(LKV * 2 / 16));
  {
    int n = M * DIM;
    cast_bf16<<<(n / 4 + 255) / 256, 256, 0, stream>>>(x, xb, n);
    transpose_cast<<<dim3(3 * DIM / 32, DIM / 32), 256, 0, stream>>>(w_qkv, wqkvT, DIM, 3 * DIM);
    transpose_cast<<<dim3(DIM / 32, DIM / 32), 256, 0, stream>>>(w_proj, wprojT, DIM, DIM);
    wpool_transpose<<<(3 * 27 * 64 + 255) / 256, 256, 0, stream>>>(
        pool_q_w, pool_k_w, pool_v_w, wpoolT);
  }

  gemm_mfma<1><<<dim3(3 * DIM / 128, M / 128), 256, 0, stream>>>(
      xb, wqkvT, b_qkv, nullptr, padQ, M, 3 * DIM, DIM);

  {
    int wq = BATCH * NH * NQ;
    pool_ln_pad<1, 0><<<(wq + 3) / 4, 256, 0, stream>>>(
        padQ, qpb, wpoolT, norm_q_g, norm_q_b, 14, 14);
    int wk = BATCH * NH * LK;
    pool_ln_pad<2, 0><<<(wk + 3) / 4, 256, 0, stream>>>(
        padQ + PS, kpb, wpoolT + 27 * 64, norm_k_g, norm_k_b, 7, 7);
    pool_ln_pad<2, 1><<<(wk + 3) / 4, 256, 0, stream>>>(
        padQ + 2 * PS, vTb, wpoolT + 2 * 27 * 64, norm_v_g, norm_v_b, 7, 7);
  }

  rel_gemm<<<(BATCH * NH * NQ) / 128, 256, 0, stream>>>(
      qpb, rel_h, rel_w, rel_t, relb);

  attn_mfma<<<dim3(NQ / 32, BATCH * NH), 256, 0, stream>>>(qpb, kpb, vTb, relb, attn_outb);

  gemm_mfma<0><<<dim3(DIM / 128, M / 128), 256, 0, stream>>>(
      attn_outb, wprojT, b_proj, out, nullptr, M, DIM, DIM);
}

// Round 5
// 427.276 us; speedup vs baseline: 1.4388x; 1.1630x over previous
//
#include <hip/hip_runtime.h>
#include <hip/hip_bf16.h>

#define BATCH 8
#define NH 12
#define DIM 768
#define HD 64
#define NQ 1568       // 8*14*14
#define TT 8
#define HH_ 14
#define WW_ 14
#define LK 392        // 8*7*7
#define LKP 416       // padded V^T row pitch (13*32), zero tail
#define SCALE 0.125f
#define EPS 1e-5f

// compact qkv layout: [s][bh][n (t*196+y*14+x)][c], QKVS elems per s-third
#define QKVS ((size_t)BATCH * NH * NQ * HD)

typedef __bf16 bf16x8 __attribute__((ext_vector_type(8)));
typedef float f32x4 __attribute__((ext_vector_type(4)));

__device__ inline ushort f2bf(float f) {
  __bf16 h = (__bf16)f;              // native v_cvt (RNE), 1 VALU op
  return __builtin_bit_cast(ushort, h);
}
__device__ inline float bf2f(ushort v) { return __uint_as_float((uint)v << 16); }
__device__ inline float bfl(uint u) { return __uint_as_float(u << 16); }
__device__ inline float bfh(uint u) { return __uint_as_float(u & 0xffff0000u); }

// async global->LDS, 16B per lane; LDS dest = wave-uniform base + lane*16
__device__ inline void gload_lds16(const ushort* g, ushort* l) {
  __builtin_amdgcn_global_load_lds(
      (const __attribute__((address_space(1))) void*)g,
      (__attribute__((address_space(3))) void*)l, 16, 0, 0);
}

// ---------------- zero fill ----------------
__global__ __launch_bounds__(256) void zero_kernel(uint4* __restrict__ p, int n16) {
  int i = blockIdx.x * 256 + threadIdx.x;
  int stride = gridDim.x * 256;
  for (; i < n16; i += stride) p[i] = make_uint4(0, 0, 0, 0);
}

// ---------------- cast fp32 -> bf16 ----------------
__global__ __launch_bounds__(256) void cast_bf16(const float* __restrict__ in,
                                                 ushort* __restrict__ outb, int n) {
  int i = (blockIdx.x * blockDim.x + threadIdx.x) * 4;
  if (i >= n) return;
  float4 v = *(const float4*)(in + i);
  ushort4 o = make_ushort4(f2bf(v.x), f2bf(v.y), f2bf(v.z), f2bf(v.w));
  *(ushort4*)(outb + i) = o;
}

// ---------------- transpose + cast: in[R][C] fp32 -> out[C][R] bf16 ----------------
__global__ __launch_bounds__(256) void transpose_cast(const float* __restrict__ in,
                                                      ushort* __restrict__ outb,
                                                      int R, int C) {
  __shared__ float tile[32][33];
  int tx = threadIdx.x & 31, ty = threadIdx.x >> 5;
  int bx = blockIdx.x * 32;
  int by = blockIdx.y * 32;
#pragma unroll
  for (int r = 0; r < 4; ++r)
    tile[ty + r * 8][tx] = in[(size_t)(by + ty + r * 8) * C + bx + tx];
  __syncthreads();
#pragma unroll
  for (int r = 0; r < 4; ++r)
    outb[(size_t)(bx + ty + r * 8) * R + by + tx] = f2bf(tile[tx][ty + r * 8]);
}

// ---------------- pool-weight transpose: [c][27] -> [tap][c], 3 tensors ----------------
__global__ __launch_bounds__(256) void wpool_transpose(const float* __restrict__ wq,
                                                       const float* __restrict__ wk,
                                                       const float* __restrict__ wv,
                                                       float* __restrict__ wT) {
  int i = blockIdx.x * blockDim.x + threadIdx.x;
  if (i >= 3 * 27 * 64) return;
  int s = i / (27 * 64), r = i % (27 * 64), tap = r / 64, c = r % 64;
  const float* src = (s == 0) ? wq : ((s == 1) ? wk : wv);
  wT[i] = src[c * 27 + tap];
}

// ---------------- bf16 MFMA GEMM (global_load_lds, linear LDS) ------
// EPI=0: fp32 out row-major. EPI=1: bf16 scatter into compact [s][bh][n][c].
template<int EPI>
__global__ __launch_bounds__(256) void gemm_mfma(const ushort* __restrict__ A,
                                                 const ushort* __restrict__ Bt,
                                                 const float* __restrict__ bias,
                                                 float* __restrict__ outf,
                                                 ushort* __restrict__ outp,
                                                 int M, int N, int K) {
  __shared__ ushort As[128 * 32];   // linear, pitch 32 (required by global_load_lds)
  __shared__ ushort Bs[128 * 32];
  const int tid = threadIdx.x;
  const int wave = tid >> 6, lane = tid & 63;
  const int quad = lane >> 4, l16 = lane & 15;
  const int row0 = blockIdx.y * 128;
  const int col0 = blockIdx.x * 128;
  const int wm = (wave & 1) * 64;
  const int wn = (wave >> 1) * 64;

  f32x4 acc[4][4];
#pragma unroll
  for (int i = 0; i < 4; ++i)
#pragma unroll
    for (int j = 0; j < 4; ++j) acc[i][j] = (f32x4){0.f, 0.f, 0.f, 0.f};

  // staging geometry: wave w issue i covers rows i*64 + w*16 + (lane>>2), col (lane&3)*8
  const int srow = (wave << 4) + (lane >> 2);
  const int scol = (lane & 3) << 3;
  ushort* ldsA = As + wave * 512;      // + i*2048 for second issue
  ushort* ldsB = Bs + wave * 512;
  const ushort* gA = A + (size_t)(row0 + srow) * K + scol;
  const ushort* gB = Bt + (size_t)(col0 + srow) * K + scol;

  for (int k0 = 0; k0 < K; k0 += 32) {
    __syncthreads();                       // prev-tile reads complete
    gload_lds16(gA + k0, ldsA);
    gload_lds16(gA + (size_t)64 * K + k0, ldsA + 2048);
    gload_lds16(gB + k0, ldsB);
    gload_lds16(gB + (size_t)64 * K + k0, ldsB + 2048);
    __syncthreads();                       // drains vmcnt(0): tile visible
    bf16x8 af[4], bfr[4];
#pragma unroll
    for (int i = 0; i < 4; ++i)
      af[i] = *(const bf16x8*)&As[(wm + i * 16 + l16) * 32 + quad * 8];
#pragma unroll
    for (int j = 0; j < 4; ++j)
      bfr[j] = *(const bf16x8*)&Bs[(wn + j * 16 + l16) * 32 + quad * 8];
#pragma unroll
    for (int i = 0; i < 4; ++i)
#pragma unroll
      for (int j = 0; j < 4; ++j)
        acc[i][j] = __builtin_amdgcn_mfma_f32_16x16x32_bf16(af[i], bfr[j], acc[i][j], 0, 0, 0);
  }

#pragma unroll
  for (int i = 0; i < 4; ++i) {
#pragma unroll
    for (int j = 0; j < 4; ++j) {
      int col = col0 + wn + j * 16 + l16;
      float bv = bias[col];
#pragma unroll
      for (int r = 0; r < 4; ++r) {
        int row = row0 + wm + i * 16 + quad * 4 + r;
        float val = acc[i][j][r] + bv;
        if (EPI == 0) {
          outf[(size_t)row * N + col] = val;
        } else {
          int b = row / NQ, nn = row % NQ;
          int s = col / DIM, rr = col % DIM;
          int h = rr >> 6, cc = rr & 63;
          size_t pidx = (((size_t)s * BATCH * NH + b * NH + h) * NQ + nn) * (size_t)HD + cc;
          outp[pidx] = f2bf(val);
        }
      }
    }
  }
}

// ---------------- row-per-wave depthwise pool + LayerNorm(64) -> bf16 ----------------
// One wave computes a full output x-row (OWW outputs) for one (bh, ot, oy).
// Each input tap is loaded ONCE and contributes to up to 3 outputs (registers).
// Zero-padding is implicit: out-of-range (dt,dy) rows are skipped wave-uniformly,
// out-of-range x taps simply have no contribution in the unrolled mapping.
template<int SW, int OWW, int VT>
__global__ __launch_bounds__(256) void pool_ln_row(const ushort* __restrict__ in,
                                                   ushort* __restrict__ out,
                                                   const float* __restrict__ wT,
                                                   const float* __restrict__ g,
                                                   const float* __restrict__ bb) {
  const int OH = OWW;               // square spatial output
  const int wid = (blockIdx.x * blockDim.x + threadIdx.x) >> 6;
  const int lane = threadIdx.x & 63;
  const int rowsTot = BATCH * NH * TT * OH;
  if (wid >= rowsTot) return;
  const int bh = wid / (TT * OH);
  const int rr = wid % (TT * OH);
  const int ot = rr / OH, oy = rr % OH;
  const int c = lane;

  float wv[27];
#pragma unroll
  for (int i = 0; i < 27; ++i) wv[i] = wT[i * 64 + c];

  float acc[OWW];
#pragma unroll
  for (int o = 0; o < OWW; ++o) acc[o] = 0.f;

  const ushort* bhbase = in + (size_t)bh * NQ * HD + c;
#pragma unroll
  for (int dt = 0; dt < 3; ++dt) {
    int tt = ot + dt - 1;
    if (tt < 0 || tt >= TT) continue;
#pragma unroll
    for (int dy = 0; dy < 3; ++dy) {
      int yy = oy * SW + dy - 1;
      if (yy < 0 || yy >= HH_) continue;
      const ushort* rowb = bhbase + (size_t)(tt * (HH_ * WW_) + yy * WW_) * HD;
      const float* wrow = &wv[(dt * 3 + dy) * 3];
#pragma unroll
      for (int xx = 0; xx < WW_; ++xx) {
        float v = bf2f(rowb[(size_t)xx * HD]);
#pragma unroll
        for (int dx = 0; dx < 3; ++dx) {
          int num = xx + 1 - dx;           // = ox*SW
          if (SW == 1) {
            if (num >= 0 && num < OWW) acc[num] += v * wrow[dx];
          } else {
            if (num >= 0 && (num & 1) == 0 && (num >> 1) < OWW)
              acc[num >> 1] += v * wrow[dx];
          }
        }
      }
    }
  }

  // LayerNorm over c (cross-lane) + store, per output
#pragma unroll
  for (int o = 0; o < OWW; ++o) {
    float a = acc[o];
    float s = a;
#pragma unroll
    for (int off = 32; off; off >>= 1) s += __shfl_xor(s, off, 64);
    float mean = s * (1.f / 64.f);
    float d = a - mean;
    float vs = d * d;
#pragma unroll
    for (int off = 32; off; off >>= 1) vs += __shfl_xor(vs, off, 64);
    float inv = rsqrtf(vs * (1.f / 64.f) + EPS);
    float res = d * inv * g[c] + bb[c];
    int opos = (ot * OH + oy) * OWW + o;
    if (VT == 0) out[((size_t)bh * (TT * OH * OWW) + opos) * HD + c] = f2bf(res);
    else         out[((size_t)bh * HD + c) * LKP + opos] = f2bf(res);
  }
}

// ---------------- rel-pos bias via MFMA GEMM ----------------
// rel67 = Q[150528x64] . Rcat^T, Rcat = concat(Rh 26, Rw 26, Rt 15) rows x 64.
// Epilogue inverts the index map and scatters the 22 valid slots per q-row
// into rel[q*24+j].
__global__ __launch_bounds__(256) void rel_gemm(const ushort* __restrict__ qp,
                                                const float* __restrict__ Rh,
                                                const float* __restrict__ Rw,
                                                const float* __restrict__ Rt,
                                                float* __restrict__ rel) {
  __shared__ ushort sR[80 * 72];   // [n][k] bf16, pitch 72 (row stride 4 banks mod 32)
  const int tid = threadIdx.x;
  const int wave = tid >> 6, lane = tid & 63;
  const int quad = lane >> 4, l16 = lane & 15;
  const int row0 = blockIdx.x * 128;

  // stage Rcat -> LDS bf16 (L2-hot, 17KB fp32)
  for (int e = tid; e < 80 * 64; e += 256) {
    int n = e >> 6, k = e & 63;
    float v;
    if (n < 26)      v = Rh[n * 64 + k];
    else if (n < 52) v = Rw[(n - 26) * 64 + k];
    else if (n < 67) v = Rt[(n - 52) * 64 + k];
    else             v = 0.f;
    sR[n * 72 + k] = f2bf(v);
  }
  __syncthreads();

  // A fragments: wave owns rows rbase..rbase+31 (2 m-frags), K=64 (2 k-steps)
  const int rbase = row0 + wave * 32;
  bf16x8 af[2][2];
#pragma unroll
  for (int m = 0; m < 2; ++m)
#pragma unroll
    for (int ks = 0; ks < 2; ++ks)
      af[m][ks] = *(const bf16x8*)(qp + (size_t)(rbase + m * 16 + l16) * HD + ks * 32 + quad * 8);

  f32x4 acc[2][5];
#pragma unroll
  for (int m = 0; m < 2; ++m)
#pragma unroll
    for (int n = 0; n < 5; ++n) acc[m][n] = (f32x4){0.f, 0.f, 0.f, 0.f};

#pragma unroll
  for (int n = 0; n < 5; ++n) {
#pragma unroll
    for (int ks = 0; ks < 2; ++ks) {
      bf16x8 bfr = *(const bf16x8*)&sR[(n * 16 + l16) * 72 + ks * 32 + quad * 8];
#pragma unroll
      for (int m = 0; m < 2; ++m)
        acc[m][n] = __builtin_amdgcn_mfma_f32_16x16x32_bf16(af[m][ks], bfr, acc[m][n], 0, 0, 0);
    }
  }

  // epilogue: C element (row = rbase + m*16 + quad*4 + r, col c = n*16 + l16)
#pragma unroll
  for (int m = 0; m < 2; ++m) {
#pragma unroll
    for (int r = 0; r < 4; ++r) {
      int q = rbase + m * 16 + quad * 4 + r;
      int n_ = q % NQ;
      int t = n_ / 196, r2 = n_ % 196, y = r2 / 14, x = r2 % 14;
      float* relq = rel + (size_t)q * 24;
#pragma unroll
      for (int n = 0; n < 5; ++n) {
        int c = n * 16 + l16;
        float val = acc[m][n][r];
        if (c < 26) {
          int dy = y + 12 - c;
          if (dy >= 0 && dy <= 12 && (dy & 1) == 0) relq[dy >> 1] = val;
        } else if (c < 52) {
          int dx = x + 12 - (c - 26);
          if (dx >= 0 && dx <= 12 && (dx & 1) == 0) relq[7 + (dx >> 1)] = val;
        } else if (c < 67) {
          int dt = t + 7 - (c - 52);
          if (dt >= 0 && dt <= 7) relq[14 + dt] = val;
        }
      }
    }
  }
}

// ---------------- MFMA attention: 32 queries/block ----
// rel staged TRANSPOSED: sRelT[j][q], pitch 36 floats. Logits read the 4
// q-rows of each fragment with ONE b128 per rel term. V loads inline in PV.
__global__ __launch_bounds__(256) void attn_mfma(const ushort* __restrict__ qp,
                                                 const ushort* __restrict__ kp,
                                                 const ushort* __restrict__ vT,
                                                 const float* __restrict__ rel,
                                                 ushort* __restrict__ outb) {
  __shared__ ushort sP[32][424];     // pitch 424: P-read (b128) spreads all banks
  __shared__ float sRelT[24][36];
  __shared__ float sMax[32][4];
  __shared__ float sSum[32][4];
  const int qb = blockIdx.x;        // 0..48
  const int bh = blockIdx.y;        // 0..95
  const int b = bh / NH, h = bh % NH;
  const int tid = threadIdx.x;
  const int w = tid >> 6, lane = tid & 63;
  const int quad = lane >> 4, l16 = lane & 15;
  const int q0 = qb * 32;

  // Q A-fragments direct from global (same for all waves; 4x redundant, tiny)
  const ushort* qbase = qp + ((size_t)bh * NQ + q0) * HD;
  bf16x8 af[2][2];
#pragma unroll
  for (int t = 0; t < 2; ++t) {
    af[t][0] = *(const bf16x8*)(qbase + (size_t)(t * 16 + l16) * HD + quad * 8);
    af[t][1] = *(const bf16x8*)(qbase + (size_t)(t * 16 + l16) * HD + 32 + quad * 8);
  }

  // rel staging, transposed: coalesced global reads (row-major in rel)
  const float* relbase = rel + ((size_t)bh * NQ + q0) * 24;
  for (int e = tid; e < 32 * 22; e += 256) {
    int row = e / 22, j = e % 22;
    sRelT[j][row] = relbase[row * 24 + j];
  }
  // zero P pad cols 400..415
  if (tid < 64) {
    int row = tid >> 1, seg = tid & 1;
    *(uint4*)&sP[row][400 + seg * 8] = make_uint4(0, 0, 0, 0);
  }

  f32x4 acc[7][2];
#pragma unroll
  for (int c = 0; c < 7; ++c)
#pragma unroll
    for (int t = 0; t < 2; ++t) acc[c][t] = (f32x4){0.f, 0.f, 0.f, 0.f};

  // ---- QK^T: wave w owns tiles tg = c*4+w; K B-fragments direct from global ----
  const ushort* kbase = kp + (size_t)bh * LK * HD;
#pragma unroll
  for (int c = 0; c < 7; ++c) {
    int tg = c * 4 + w;
    if (tg < 25) {
      int kg = tg * 16 + l16;
      int kgc = kg < LK ? kg : (LK - 1);   // clamp; masked below
      const ushort* krow = kbase + (size_t)kgc * HD;
      bf16x8 b0 = *(const bf16x8*)(krow + quad * 8);
      bf16x8 b1 = *(const bf16x8*)(krow + 32 + quad * 8);
#pragma unroll
      for (int t = 0; t < 2; ++t) {
        acc[c][t] = __builtin_amdgcn_mfma_f32_16x16x32_bf16(af[t][0], b0, acc[c][t], 0, 0, 0);
        acc[c][t] = __builtin_amdgcn_mfma_f32_16x16x32_bf16(af[t][1], b1, acc[c][t], 0, 0, 0);
      }
    }
  }
  __syncthreads();   // barrier 1: sRelT (and sP pad) visible

  // ---- logits: scale + rel bias, one b128 per term per (c,t) ----
#pragma unroll
  for (int c = 0; c < 7; ++c) {
    int tg = c * 4 + w;
    int kg = tg * 16 + l16;
    if (tg < 25) {
      int kgc = kg < LK ? kg : 0;
      bool ok = kg < LK;
      int kt = kgc / 49, kyx = kgc % 49, ky = kyx / 7, kx = kyx % 7;
#pragma unroll
      for (int t = 0; t < 2; ++t) {
        f32x4 bh4 = *(const f32x4*)&sRelT[ky][t * 16 + quad * 4];
        f32x4 bw4 = *(const f32x4*)&sRelT[7 + kx][t * 16 + quad * 4];
        f32x4 bt4 = *(const f32x4*)&sRelT[14 + kt][t * 16 + quad * 4];
#pragma unroll
        for (int r = 0; r < 4; ++r)
          acc[c][t][r] = ok ? (acc[c][t][r] * SCALE + bh4[r] + bw4[r] + bt4[r]) : -1e30f;
      }
    } else {
#pragma unroll
      for (int t = 0; t < 2; ++t)
#pragma unroll
        for (int r = 0; r < 4; ++r) acc[c][t][r] = -1e30f;
    }
  }

  // ---- row max: reduce over l16, exchange across waves ----
  float pmax[2][4];
#pragma unroll
  for (int t = 0; t < 2; ++t)
#pragma unroll
    for (int r = 0; r < 4; ++r) {
      float m = acc[0][t][r];
#pragma unroll
      for (int c = 1; c < 7; ++c) m = fmaxf(m, acc[c][t][r]);
#pragma unroll
      for (int off = 1; off < 16; off <<= 1) m = fmaxf(m, __shfl_xor(m, off, 64));
      pmax[t][r] = m;
    }
  if (l16 == 0) {
#pragma unroll
    for (int t = 0; t < 2; ++t)
#pragma unroll
      for (int r = 0; r < 4; ++r) sMax[t * 16 + quad * 4 + r][w] = pmax[t][r];
  }
  __syncthreads();   // barrier 2

  float M[2][4];
#pragma unroll
  for (int t = 0; t < 2; ++t)
#pragma unroll
    for (int r = 0; r < 4; ++r) {
      float4 mm = *(float4*)&sMax[t * 16 + quad * 4 + r][0];
      M[t][r] = fmaxf(fmaxf(mm.x, mm.y), fmaxf(mm.z, mm.w));
    }

  // ---- exp, partial sums, P write ----
  float psum[2][4];
#pragma unroll
  for (int t = 0; t < 2; ++t)
#pragma unroll
    for (int r = 0; r < 4; ++r) psum[t][r] = 0.f;
#pragma unroll
  for (int c = 0; c < 7; ++c) {
#pragma unroll
    for (int t = 0; t < 2; ++t)
#pragma unroll
      for (int r = 0; r < 4; ++r) {
        float e = __expf(acc[c][t][r] - M[t][r]);
        acc[c][t][r] = e;
        psum[t][r] += e;
      }
  }
#pragma unroll
  for (int t = 0; t < 2; ++t)
#pragma unroll
    for (int r = 0; r < 4; ++r) {
      float s = psum[t][r];
#pragma unroll
      for (int off = 1; off < 16; off <<= 1) s += __shfl_xor(s, off, 64);
      psum[t][r] = s;
    }
  if (l16 == 0) {
#pragma unroll
    for (int t = 0; t < 2; ++t)
#pragma unroll
      for (int r = 0; r < 4; ++r) sSum[t * 16 + quad * 4 + r][w] = psum[t][r];
  }
#pragma unroll
  for (int c = 0; c < 7; ++c) {
    int tg = c * 4 + w;
    if (tg < 25) {
      int kg = tg * 16 + l16;
#pragma unroll
      for (int t = 0; t < 2; ++t)
#pragma unroll
        for (int r = 0; r < 4; ++r)
          sP[t * 16 + quad * 4 + r][kg] = f2bf(acc[c][t][r]);
    }
  }
  __syncthreads();   // barrier 3

  float rinv[2][4];
#pragma unroll
  for (int t = 0; t < 2; ++t)
#pragma unroll
    for (int r = 0; r < 4; ++r) {
      float4 ss = *(float4*)&sSum[t * 16 + quad * 4 + r][0];
      rinv[t][r] = 1.f / (ss.x + ss.y + ss.z + ss.w);
    }

  // ---- PV: V^T B-fragments direct from global (padded pitch LKP, zero tail) ----
  f32x4 oacc[2];
  oacc[0] = (f32x4){0.f, 0.f, 0.f, 0.f};
  oacc[1] = (f32x4){0.f, 0.f, 0.f, 0.f};
  const ushort* vrow = vT + ((size_t)bh * HD + w * 16 + l16) * LKP;
#pragma unroll
  for (int s = 0; s < 13; ++s) {
    int kb = s * 32;
    bf16x8 vb = *(const bf16x8*)(vrow + kb + quad * 8);
#pragma unroll
    for (int t = 0; t < 2; ++t) {
      bf16x8 pa = *(const bf16x8*)&sP[t * 16 + l16][kb + quad * 8];
      oacc[t] = __builtin_amdgcn_mfma_f32_16x16x32_bf16(pa, vb, oacc[t], 0, 0, 0);
    }
  }

#pragma unroll
  for (int t = 0; t < 2; ++t)
#pragma unroll
    for (int r = 0; r < 4; ++r) {
      int q = q0 + t * 16 + quad * 4 + r;
      outb[((size_t)b * NQ + q) * DIM + h * HD + w * 16 + l16] = f2bf(oacc[t][r] * rinv[t][r]);
    }
}

// ---------------- launch ----------------
extern "C" void kernel_launch(void* const* d_in, const int* in_sizes, int n_in,
                              void* d_out, int out_size, void* d_ws, size_t ws_size,
                              hipStream_t stream) {
  const float* x        = (const float*)d_in[0];
  const float* w_qkv    = (const float*)d_in[1];
  const float* b_qkv    = (const float*)d_in[2];
  const float* pool_q_w = (const float*)d_in[3];
  const float* pool_k_w = (const float*)d_in[4];
  const float* pool_v_w = (const float*)d_in[5];
  const float* norm_q_g = (const float*)d_in[6];
  const float* norm_q_b = (const float*)d_in[7];
  const float* norm_k_g = (const float*)d_in[8];
  const float* norm_k_b = (const float*)d_in[9];
  const float* norm_v_g = (const float*)d_in[10];
  const float* norm_v_b = (const float*)d_in[11];
  const float* rel_h    = (const float*)d_in[12];
  const float* rel_w    = (const float*)d_in[13];
  const float* rel_t    = (const float*)d_in[14];
  const float* w_proj   = (const float*)d_in[15];
  const float* b_proj   = (const float*)d_in[16];
  float* out = (float*)d_out;

  const size_t NT  = (size_t)BATCH * NH * NQ * HD;
  const size_t LKT = (size_t)BATCH * NH * LK * HD;
  const size_t LKV = (size_t)BATCH * NH * HD * LKP;   // padded V^T
  const size_t RELN = (size_t)BATCH * NH * NQ * 24;

  ushort* qkvb = (ushort*)d_ws;                 // 3*QKVS bf16 (compact)
  ushort* qpb  = qkvb + 3 * QKVS;               // NT bf16
  ushort* kpb  = qpb + NT;                      // LKT bf16
  ushort* vTb  = kpb + LKT;                     // LKV bf16 ([bh][c][kpos], pitch LKP)
  float*  relb = (float*)(vTb + LKV);           // RELN fp32
  ushort* wqkvT = (ushort*)(relb + RELN);
  ushort* wprojT = wqkvT + (size_t)DIM * 3 * DIM;
  float*  wpoolT = (float*)(wprojT + (size_t)DIM * DIM);
  ushort* xb = qpb;                   // overlay: dead before pool writes qpb
  ushort* attn_outb = qkvb;           // overlay: qkvb dead after pools

  const int M = BATCH * NQ;  // 12544

  zero_kernel<<<256, 256, 0, stream>>>((uint4*)vTb, (int)(LKV * 2 / 16));
  {
    int n = M * DIM;
    cast_bf16<<<(n / 4 + 255) / 256, 256, 0, stream>>>(x, xb, n);
    transpose_cast<<<dim3(3 * DIM / 32, DIM / 32), 256, 0, stream>>>(w_qkv, wqkvT, DIM, 3 * DIM);
    transpose_cast<<<dim3(DIM / 32, DIM / 32), 256, 0, stream>>>(w_proj, wprojT, DIM, DIM);
    wpool_transpose<<<(3 * 27 * 64 + 255) / 256, 256, 0, stream>>>(
        pool_q_w, pool_k_w, pool_v_w, wpoolT);
  }

  gemm_mfma<1><<<dim3(3 * DIM / 128, M / 128), 256, 0, stream>>>(
      xb, wqkvT, b_qkv, nullptr, qkvb, M, 3 * DIM, DIM);

  {
    // q: 96*8*14 = 10752 row-waves -> 2688 blocks
    pool_ln_row<1, 14, 0><<<(BATCH * NH * TT * 14) / 4, 256, 0, stream>>>(
        qkvb, qpb, wpoolT, norm_q_g, norm_q_b);
    // k: 96*8*7 = 5376 row-waves -> 1344 blocks
    pool_ln_row<2, 7, 0><<<(BATCH * NH * TT * 7) / 4, 256, 0, stream>>>(
        qkvb + QKVS, kpb, wpoolT + 27 * 64, norm_k_g, norm_k_b);
    pool_ln_row<2, 7, 1><<<(BATCH * NH * TT * 7) / 4, 256, 0, stream>>>(
        qkvb + 2 * QKVS, vTb, wpoolT + 2 * 27 * 64, norm_v_g, norm_v_b);
  }

  rel_gemm<<<(BATCH * NH * NQ) / 128, 256, 0, stream>>>(
      qpb, rel_h, rel_w, rel_t, relb);

  attn_mfma<<<dim3(NQ / 32, BATCH * NH), 256, 0, stream>>>(qpb, kpb, vTb, relb, attn_outb);

  gemm_mfma<0><<<dim3(DIM / 128, M / 128), 256, 0, stream>>>(
      attn_outb, wprojT, b_proj, out, nullptr, M, DIM, DIM);
}

// Round 6
// 409.135 us; speedup vs baseline: 1.5026x; 1.0443x over previous
//
#include <hip/hip_runtime.h>
#include <hip/hip_bf16.h>

#define BATCH 8
#define NH 12
#define DIM 768
#define HD 64
#define NQ 1568       // 8*14*14
#define TT 8
#define HH_ 14
#define WW_ 14
#define LK 392        // 8*7*7
#define LKP 416       // padded V^T row pitch (13*32), zero tail
#define SCALE 0.125f
#define EPS 1e-5f

// compact qkv layout: [s][bh][n (t*196+y*14+x)][c], QKVS elems per s-third
#define QKVS ((size_t)BATCH * NH * NQ * HD)

// prep kernel block-role partition
#define NB_CAST 2048
#define NB_TQKV 1728      // (3*DIM/32)*(DIM/32) = 72*24
#define NB_TPROJ 576      // 24*24
#define NB_ZERO 64
#define NB_WPOOL 21

typedef __bf16 bf16x8 __attribute__((ext_vector_type(8)));
typedef float f32x4 __attribute__((ext_vector_type(4)));

__device__ inline ushort f2bf(float f) {
  __bf16 h = (__bf16)f;              // native v_cvt (RNE), 1 VALU op
  return __builtin_bit_cast(ushort, h);
}
__device__ inline float bf2f(ushort v) { return __uint_as_float((uint)v << 16); }

// async global->LDS, 16B per lane; LDS dest = wave-uniform base + lane*16
__device__ inline void gload_lds16(const ushort* g, ushort* l) {
  __builtin_amdgcn_global_load_lds(
      (const __attribute__((address_space(1))) void*)g,
      (__attribute__((address_space(3))) void*)l, 16, 0, 0);
}

// ---------------- merged prep: cast | w transposes | zero vT | wpool ----------------
__global__ __launch_bounds__(256) void prep_kernel(
    const float* __restrict__ x, const float* __restrict__ w_qkv,
    const float* __restrict__ w_proj,
    const float* __restrict__ wq, const float* __restrict__ wk,
    const float* __restrict__ wv,
    ushort* __restrict__ xb, ushort* __restrict__ wqkvT,
    ushort* __restrict__ wprojT, float* __restrict__ wT,
    uint4* __restrict__ zp, int nzero16, int ncast4) {
  __shared__ float tile[32][33];
  int bid = blockIdx.x;
  const int tid = threadIdx.x;
  if (bid < NB_CAST) {
    for (int i = bid * 256 + tid; i < ncast4; i += NB_CAST * 256) {
      float4 v = *(const float4*)(x + (size_t)i * 4);
      *(ushort4*)(xb + (size_t)i * 4) =
          make_ushort4(f2bf(v.x), f2bf(v.y), f2bf(v.z), f2bf(v.w));
    }
    return;
  }
  bid -= NB_CAST;
  if (bid < NB_TQKV + NB_TPROJ) {
    const float* in; ushort* outb; int R, C, bx, by;
    if (bid < NB_TQKV) { in = w_qkv; outb = wqkvT; R = DIM; C = 3 * DIM;
                         bx = (bid % 72) * 32; by = (bid / 72) * 32; }
    else { int b2 = bid - NB_TQKV; in = w_proj; outb = wprojT; R = DIM; C = DIM;
           bx = (b2 % 24) * 32; by = (b2 / 24) * 32; }
    int tx = tid & 31, ty = tid >> 5;
#pragma unroll
    for (int r = 0; r < 4; ++r)
      tile[ty + r * 8][tx] = in[(size_t)(by + ty + r * 8) * C + bx + tx];
    __syncthreads();
#pragma unroll
    for (int r = 0; r < 4; ++r)
      outb[(size_t)(bx + ty + r * 8) * R + by + tx] = f2bf(tile[tx][ty + r * 8]);
    return;
  }
  bid -= NB_TQKV + NB_TPROJ;
  if (bid < NB_ZERO) {
    for (int i = bid * 256 + tid; i < nzero16; i += NB_ZERO * 256)
      zp[i] = make_uint4(0, 0, 0, 0);
    return;
  }
  bid -= NB_ZERO;
  {
    int i = bid * 256 + tid;
    if (i < 3 * 27 * 64) {
      int s = i / (27 * 64), r = i % (27 * 64), tap = r / 64, c = r % 64;
      const float* src = (s == 0) ? wq : ((s == 1) ? wk : wv);
      wT[i] = src[c * 27 + tap];
    }
  }
}

// ---------------- bf16 MFMA GEMM: 2-phase double-buffered (T3-minimal) ------
// stage(next) -> ds_read+MFMA(cur) -> syncthreads (vmcnt0+lgkm drain).
// One barrier per K-iter; next tile's load latency hides under MFMAs.
// EPI=0: fp32 out row-major. EPI=1: bf16 scatter into compact [s][bh][n][c].
template<int EPI>
__global__ __launch_bounds__(256) void gemm_mfma(const ushort* __restrict__ A,
                                                 const ushort* __restrict__ Bt,
                                                 const float* __restrict__ bias,
                                                 float* __restrict__ outf,
                                                 ushort* __restrict__ outp,
                                                 int M, int N, int K) {
  __shared__ ushort As[2][128 * 32];   // linear pitch 32 (global_load_lds dest)
  __shared__ ushort Bs[2][128 * 32];
  const int tid = threadIdx.x;
  const int wave = tid >> 6, lane = tid & 63;
  const int quad = lane >> 4, l16 = lane & 15;
  const int row0 = blockIdx.y * 128;
  const int col0 = blockIdx.x * 128;
  const int wm = (wave & 1) * 64;
  const int wn = (wave >> 1) * 64;

  f32x4 acc[4][4];
#pragma unroll
  for (int i = 0; i < 4; ++i)
#pragma unroll
    for (int j = 0; j < 4; ++j) acc[i][j] = (f32x4){0.f, 0.f, 0.f, 0.f};

  // staging geometry: wave w issue i covers rows i*64 + w*16 + (lane>>2), col (lane&3)*8
  const int srow = (wave << 4) + (lane >> 2);
  const int scol = (lane & 3) << 3;
  const ushort* gA = A + (size_t)(row0 + srow) * K + scol;
  const ushort* gB = Bt + (size_t)(col0 + srow) * K + scol;

  // prologue: stage tile 0 into buf 0
  gload_lds16(gA, &As[0][wave * 512]);
  gload_lds16(gA + (size_t)64 * K, &As[0][wave * 512 + 2048]);
  gload_lds16(gB, &Bs[0][wave * 512]);
  gload_lds16(gB + (size_t)64 * K, &Bs[0][wave * 512 + 2048]);
  __syncthreads();                       // drains prologue stage (vmcnt 0)

  int cur = 0;
  for (int k0 = 0; k0 < K; k0 += 32) {
    if (k0 + 32 < K) {                   // issue next tile into other buffer
      int nb = cur ^ 1;
      gload_lds16(gA + k0 + 32, &As[nb][wave * 512]);
      gload_lds16(gA + (size_t)64 * K + k0 + 32, &As[nb][wave * 512 + 2048]);
      gload_lds16(gB + k0 + 32, &Bs[nb][wave * 512]);
      gload_lds16(gB + (size_t)64 * K + k0 + 32, &Bs[nb][wave * 512 + 2048]);
    }
    bf16x8 af[4], bfr[4];
#pragma unroll
    for (int i = 0; i < 4; ++i)
      af[i] = *(const bf16x8*)&As[cur][(wm + i * 16 + l16) * 32 + quad * 8];
#pragma unroll
    for (int j = 0; j < 4; ++j)
      bfr[j] = *(const bf16x8*)&Bs[cur][(wn + j * 16 + l16) * 32 + quad * 8];
#pragma unroll
    for (int i = 0; i < 4; ++i)
#pragma unroll
      for (int j = 0; j < 4; ++j)
        acc[i][j] = __builtin_amdgcn_mfma_f32_16x16x32_bf16(af[i], bfr[j], acc[i][j], 0, 0, 0);
    __syncthreads();                     // drains stage (vmcnt0) + all lgkm
    cur ^= 1;
  }

#pragma unroll
  for (int i = 0; i < 4; ++i) {
#pragma unroll
    for (int j = 0; j < 4; ++j) {
      int col = col0 + wn + j * 16 + l16;
      float bv = bias[col];
#pragma unroll
      for (int r = 0; r < 4; ++r) {
        int row = row0 + wm + i * 16 + quad * 4 + r;
        float val = acc[i][j][r] + bv;
        if (EPI == 0) {
          outf[(size_t)row * N + col] = val;
        } else {
          int b = row / NQ, nn = row % NQ;
          int s = col / DIM, rr = col % DIM;
          int h = rr >> 6, cc = rr & 63;
          size_t pidx = (((size_t)s * BATCH * NH + b * NH + h) * NQ + nn) * (size_t)HD + cc;
          outp[pidx] = f2bf(val);
        }
      }
    }
  }
}

// ---------------- row-per-wave depthwise pool + LayerNorm(64) -> bf16 ----------------
// One wave computes a full output x-row (OWW outputs) for one (bh, ot, oy).
// oscale folds attention's softmax SCALE into K (0.125 = 2^-3, exact in bf16).
template<int SW, int OWW, int VT>
__global__ __launch_bounds__(256) void pool_ln_row(const ushort* __restrict__ in,
                                                   ushort* __restrict__ out,
                                                   const float* __restrict__ wT,
                                                   const float* __restrict__ g,
                                                   const float* __restrict__ bb,
                                                   float oscale) {
  const int OH = OWW;               // square spatial output
  const int wid = (blockIdx.x * blockDim.x + threadIdx.x) >> 6;
  const int lane = threadIdx.x & 63;
  const int rowsTot = BATCH * NH * TT * OH;
  if (wid >= rowsTot) return;
  const int bh = wid / (TT * OH);
  const int rr = wid % (TT * OH);
  const int ot = rr / OH, oy = rr % OH;
  const int c = lane;

  float wv[27];
#pragma unroll
  for (int i = 0; i < 27; ++i) wv[i] = wT[i * 64 + c];

  float acc[OWW];
#pragma unroll
  for (int o = 0; o < OWW; ++o) acc[o] = 0.f;

  const ushort* bhbase = in + (size_t)bh * NQ * HD + c;
#pragma unroll
  for (int dt = 0; dt < 3; ++dt) {
    int tt = ot + dt - 1;
    if (tt < 0 || tt >= TT) continue;
#pragma unroll
    for (int dy = 0; dy < 3; ++dy) {
      int yy = oy * SW + dy - 1;
      if (yy < 0 || yy >= HH_) continue;
      const ushort* rowb = bhbase + (size_t)(tt * (HH_ * WW_) + yy * WW_) * HD;
      const float* wrow = &wv[(dt * 3 + dy) * 3];
#pragma unroll
      for (int xx = 0; xx < WW_; ++xx) {
        float v = bf2f(rowb[(size_t)xx * HD]);
#pragma unroll
        for (int dx = 0; dx < 3; ++dx) {
          int num = xx + 1 - dx;           // = ox*SW
          if (SW == 1) {
            if (num >= 0 && num < OWW) acc[num] += v * wrow[dx];
          } else {
            if (num >= 0 && (num & 1) == 0 && (num >> 1) < OWW)
              acc[num >> 1] += v * wrow[dx];
          }
        }
      }
    }
  }

  // LayerNorm over c (cross-lane) + store, per output
#pragma unroll
  for (int o = 0; o < OWW; ++o) {
    float a = acc[o];
    float s = a;
#pragma unroll
    for (int off = 32; off; off >>= 1) s += __shfl_xor(s, off, 64);
    float mean = s * (1.f / 64.f);
    float d = a - mean;
    float vs = d * d;
#pragma unroll
    for (int off = 32; off; off >>= 1) vs += __shfl_xor(vs, off, 64);
    float inv = rsqrtf(vs * (1.f / 64.f) + EPS);
    float res = (d * inv * g[c] + bb[c]) * oscale;
    int opos = (ot * OH + oy) * OWW + o;
    if (VT == 0) out[((size_t)bh * (TT * OH * OWW) + opos) * HD + c] = f2bf(res);
    else         out[((size_t)bh * HD + c) * LKP + opos] = f2bf(res);
  }
}

// ---------------- rel-pos bias via MFMA GEMM ----------------
// rel67 = Q[150528x64] . Rcat^T, Rcat = concat(Rh 26, Rw 26, Rt 15) rows x 64.
__global__ __launch_bounds__(256) void rel_gemm(const ushort* __restrict__ qp,
                                                const float* __restrict__ Rh,
                                                const float* __restrict__ Rw,
                                                const float* __restrict__ Rt,
                                                float* __restrict__ rel) {
  __shared__ ushort sR[80 * 72];   // [n][k] bf16, pitch 72 (row stride 4 banks mod 32)
  const int tid = threadIdx.x;
  const int wave = tid >> 6, lane = tid & 63;
  const int quad = lane >> 4, l16 = lane & 15;
  const int row0 = blockIdx.x * 128;

  // stage Rcat -> LDS bf16 (L2-hot, 17KB fp32)
  for (int e = tid; e < 80 * 64; e += 256) {
    int n = e >> 6, k = e & 63;
    float v;
    if (n < 26)      v = Rh[n * 64 + k];
    else if (n < 52) v = Rw[(n - 26) * 64 + k];
    else if (n < 67) v = Rt[(n - 52) * 64 + k];
    else             v = 0.f;
    sR[n * 72 + k] = f2bf(v);
  }
  __syncthreads();

  // A fragments: wave owns rows rbase..rbase+31 (2 m-frags), K=64 (2 k-steps)
  const int rbase = row0 + wave * 32;
  bf16x8 af[2][2];
#pragma unroll
  for (int m = 0; m < 2; ++m)
#pragma unroll
    for (int ks = 0; ks < 2; ++ks)
      af[m][ks] = *(const bf16x8*)(qp + (size_t)(rbase + m * 16 + l16) * HD + ks * 32 + quad * 8);

  f32x4 acc[2][5];
#pragma unroll
  for (int m = 0; m < 2; ++m)
#pragma unroll
    for (int n = 0; n < 5; ++n) acc[m][n] = (f32x4){0.f, 0.f, 0.f, 0.f};

#pragma unroll
  for (int n = 0; n < 5; ++n) {
#pragma unroll
    for (int ks = 0; ks < 2; ++ks) {
      bf16x8 bfr = *(const bf16x8*)&sR[(n * 16 + l16) * 72 + ks * 32 + quad * 8];
#pragma unroll
      for (int m = 0; m < 2; ++m)
        acc[m][n] = __builtin_amdgcn_mfma_f32_16x16x32_bf16(af[m][ks], bfr, acc[m][n], 0, 0, 0);
    }
  }

  // epilogue: C element (row = rbase + m*16 + quad*4 + r, col c = n*16 + l16)
#pragma unroll
  for (int m = 0; m < 2; ++m) {
#pragma unroll
    for (int r = 0; r < 4; ++r) {
      int q = rbase + m * 16 + quad * 4 + r;
      int n_ = q % NQ;
      int t = n_ / 196, r2 = n_ % 196, y = r2 / 14, x = r2 % 14;
      float* relq = rel + (size_t)q * 24;
#pragma unroll
      for (int n = 0; n < 5; ++n) {
        int c = n * 16 + l16;
        float val = acc[m][n][r];
        if (c < 26) {
          int dy = y + 12 - c;
          if (dy >= 0 && dy <= 12 && (dy & 1) == 0) relq[dy >> 1] = val;
        } else if (c < 52) {
          int dx = x + 12 - (c - 26);
          if (dx >= 0 && dx <= 12 && (dx & 1) == 0) relq[7 + (dx >> 1)] = val;
        } else if (c < 67) {
          int dt = t + 7 - (c - 52);
          if (dt >= 0 && dt <= 7) relq[14 + dt] = val;
        }
      }
    }
  }
}

// ---------------- MFMA attention: 32 queries/block ----
// K is pre-scaled by SCALE (pool epilogue) -> logits = acc + biases (no mul).
// rel staged TRANSPOSED: sRelT[j][q], pitch 36 floats; one b128 per rel term.
__global__ __launch_bounds__(256) void attn_mfma(const ushort* __restrict__ qp,
                                                 const ushort* __restrict__ kp,
                                                 const ushort* __restrict__ vT,
                                                 const float* __restrict__ rel,
                                                 ushort* __restrict__ outb) {
  __shared__ ushort sP[32][424];     // pitch 424: P-read (b128) spreads all banks
  __shared__ float sRelT[24][36];
  __shared__ float sMax[32][4];
  __shared__ float sSum[32][4];
  const int qb = blockIdx.x;        // 0..48
  const int bh = blockIdx.y;        // 0..95
  const int b = bh / NH, h = bh % NH;
  const int tid = threadIdx.x;
  const int w = tid >> 6, lane = tid & 63;
  const int quad = lane >> 4, l16 = lane & 15;
  const int q0 = qb * 32;

  // Q A-fragments direct from global (same for all waves; 4x redundant, tiny)
  const ushort* qbase = qp + ((size_t)bh * NQ + q0) * HD;
  bf16x8 af[2][2];
#pragma unroll
  for (int t = 0; t < 2; ++t) {
    af[t][0] = *(const bf16x8*)(qbase + (size_t)(t * 16 + l16) * HD + quad * 8);
    af[t][1] = *(const bf16x8*)(qbase + (size_t)(t * 16 + l16) * HD + 32 + quad * 8);
  }

  // rel staging, transposed: coalesced global reads (row-major in rel)
  const float* relbase = rel + ((size_t)bh * NQ + q0) * 24;
  for (int e = tid; e < 32 * 22; e += 256) {
    int row = e / 22, j = e % 22;
    sRelT[j][row] = relbase[row * 24 + j];
  }
  // zero P pad cols 400..415
  if (tid < 64) {
    int row = tid >> 1, seg = tid & 1;
    *(uint4*)&sP[row][400 + seg * 8] = make_uint4(0, 0, 0, 0);
  }

  f32x4 acc[7][2];
#pragma unroll
  for (int c = 0; c < 7; ++c)
#pragma unroll
    for (int t = 0; t < 2; ++t) acc[c][t] = (f32x4){0.f, 0.f, 0.f, 0.f};

  // ---- QK^T: wave w owns tiles tg = c*4+w; K B-fragments direct from global ----
  const ushort* kbase = kp + (size_t)bh * LK * HD;
#pragma unroll
  for (int c = 0; c < 7; ++c) {
    int tg = c * 4 + w;
    if (tg < 25) {
      int kg = tg * 16 + l16;
      int kgc = kg < LK ? kg : (LK - 1);   // clamp; masked below
      const ushort* krow = kbase + (size_t)kgc * HD;
      bf16x8 b0 = *(const bf16x8*)(krow + quad * 8);
      bf16x8 b1 = *(const bf16x8*)(krow + 32 + quad * 8);
#pragma unroll
      for (int t = 0; t < 2; ++t) {
        acc[c][t] = __builtin_amdgcn_mfma_f32_16x16x32_bf16(af[t][0], b0, acc[c][t], 0, 0, 0);
        acc[c][t] = __builtin_amdgcn_mfma_f32_16x16x32_bf16(af[t][1], b1, acc[c][t], 0, 0, 0);
      }
    }
  }
  __syncthreads();   // barrier 1: sRelT (and sP pad) visible

  // ---- logits: rel bias add only (K pre-scaled), one b128 per term per (c,t) ----
#pragma unroll
  for (int c = 0; c < 7; ++c) {
    int tg = c * 4 + w;
    int kg = tg * 16 + l16;
    if (tg < 25) {
      int kgc = kg < LK ? kg : 0;
      bool ok = kg < LK;
      int kt = kgc / 49, kyx = kgc % 49, ky = kyx / 7, kx = kyx % 7;
#pragma unroll
      for (int t = 0; t < 2; ++t) {
        f32x4 bh4 = *(const f32x4*)&sRelT[ky][t * 16 + quad * 4];
        f32x4 bw4 = *(const f32x4*)&sRelT[7 + kx][t * 16 + quad * 4];
        f32x4 bt4 = *(const f32x4*)&sRelT[14 + kt][t * 16 + quad * 4];
#pragma unroll
        for (int r = 0; r < 4; ++r)
          acc[c][t][r] = ok ? (acc[c][t][r] + bh4[r] + bw4[r] + bt4[r]) : -1e30f;
      }
    } else {
#pragma unroll
      for (int t = 0; t < 2; ++t)
#pragma unroll
        for (int r = 0; r < 4; ++r) acc[c][t][r] = -1e30f;
    }
  }

  // ---- row max: reduce over l16, exchange across waves ----
  float pmax[2][4];
#pragma unroll
  for (int t = 0; t < 2; ++t)
#pragma unroll
    for (int r = 0; r < 4; ++r) {
      float m = acc[0][t][r];
#pragma unroll
      for (int c = 1; c < 7; ++c) m = fmaxf(m, acc[c][t][r]);
#pragma unroll
      for (int off = 1; off < 16; off <<= 1) m = fmaxf(m, __shfl_xor(m, off, 64));
      pmax[t][r] = m;
    }
  if (l16 == 0) {
#pragma unroll
    for (int t = 0; t < 2; ++t)
#pragma unroll
      for (int r = 0; r < 4; ++r) sMax[t * 16 + quad * 4 + r][w] = pmax[t][r];
  }
  __syncthreads();   // barrier 2

  float M[2][4];
#pragma unroll
  for (int t = 0; t < 2; ++t)
#pragma unroll
    for (int r = 0; r < 4; ++r) {
      float4 mm = *(float4*)&sMax[t * 16 + quad * 4 + r][0];
      M[t][r] = fmaxf(fmaxf(mm.x, mm.y), fmaxf(mm.z, mm.w));
    }

  // ---- exp, partial sums, P write ----
  float psum[2][4];
#pragma unroll
  for (int t = 0; t < 2; ++t)
#pragma unroll
    for (int r = 0; r < 4; ++r) psum[t][r] = 0.f;
#pragma unroll
  for (int c = 0; c < 7; ++c) {
#pragma unroll
    for (int t = 0; t < 2; ++t)
#pragma unroll
      for (int r = 0; r < 4; ++r) {
        float e = __expf(acc[c][t][r] - M[t][r]);
        acc[c][t][r] = e;
        psum[t][r] += e;
      }
  }
#pragma unroll
  for (int t = 0; t < 2; ++t)
#pragma unroll
    for (int r = 0; r < 4; ++r) {
      float s = psum[t][r];
#pragma unroll
      for (int off = 1; off < 16; off <<= 1) s += __shfl_xor(s, off, 64);
      psum[t][r] = s;
    }
  if (l16 == 0) {
#pragma unroll
    for (int t = 0; t < 2; ++t)
#pragma unroll
      for (int r = 0; r < 4; ++r) sSum[t * 16 + quad * 4 + r][w] = psum[t][r];
  }
#pragma unroll
  for (int c = 0; c < 7; ++c) {
    int tg = c * 4 + w;
    if (tg < 25) {
      int kg = tg * 16 + l16;
#pragma unroll
      for (int t = 0; t < 2; ++t)
#pragma unroll
        for (int r = 0; r < 4; ++r)
          sP[t * 16 + quad * 4 + r][kg] = f2bf(acc[c][t][r]);
    }
  }
  __syncthreads();   // barrier 3

  float rinv[2][4];
#pragma unroll
  for (int t = 0; t < 2; ++t)
#pragma unroll
    for (int r = 0; r < 4; ++r) {
      float4 ss = *(float4*)&sSum[t * 16 + quad * 4 + r][0];
      rinv[t][r] = 1.f / (ss.x + ss.y + ss.z + ss.w);
    }

  // ---- PV: V^T B-fragments direct from global (padded pitch LKP, zero tail) ----
  f32x4 oacc[2];
  oacc[0] = (f32x4){0.f, 0.f, 0.f, 0.f};
  oacc[1] = (f32x4){0.f, 0.f, 0.f, 0.f};
  const ushort* vrow = vT + ((size_t)bh * HD + w * 16 + l16) * LKP;
#pragma unroll
  for (int s = 0; s < 13; ++s) {
    int kb = s * 32;
    bf16x8 vb = *(const bf16x8*)(vrow + kb + quad * 8);
#pragma unroll
    for (int t = 0; t < 2; ++t) {
      bf16x8 pa = *(const bf16x8*)&sP[t * 16 + l16][kb + quad * 8];
      oacc[t] = __builtin_amdgcn_mfma_f32_16x16x32_bf16(pa, vb, oacc[t], 0, 0, 0);
    }
  }

#pragma unroll
  for (int t = 0; t < 2; ++t)
#pragma unroll
    for (int r = 0; r < 4; ++r) {
      int q = q0 + t * 16 + quad * 4 + r;
      outb[((size_t)b * NQ + q) * DIM + h * HD + w * 16 + l16] = f2bf(oacc[t][r] * rinv[t][r]);
    }
}

// ---------------- launch ----------------
extern "C" void kernel_launch(void* const* d_in, const int* in_sizes, int n_in,
                              void* d_out, int out_size, void* d_ws, size_t ws_size,
                              hipStream_t stream) {
  const float* x        = (const float*)d_in[0];
  const float* w_qkv    = (const float*)d_in[1];
  const float* b_qkv    = (const float*)d_in[2];
  const float* pool_q_w = (const float*)d_in[3];
  const float* pool_k_w = (const float*)d_in[4];
  const float* pool_v_w = (const float*)d_in[5];
  const float* norm_q_g = (const float*)d_in[6];
  const float* norm_q_b = (const float*)d_in[7];
  const float* norm_k_g = (const float*)d_in[8];
  const float* norm_k_b = (const float*)d_in[9];
  const float* norm_v_g = (const float*)d_in[10];
  const float* norm_v_b = (const float*)d_in[11];
  const float* rel_h    = (const float*)d_in[12];
  const float* rel_w    = (const float*)d_in[13];
  const float* rel_t    = (const float*)d_in[14];
  const float* w_proj   = (const float*)d_in[15];
  const float* b_proj   = (const float*)d_in[16];
  float* out = (float*)d_out;

  const size_t NT  = (size_t)BATCH * NH * NQ * HD;
  const size_t LKT = (size_t)BATCH * NH * LK * HD;
  const size_t LKV = (size_t)BATCH * NH * HD * LKP;   // padded V^T
  const size_t RELN = (size_t)BATCH * NH * NQ * 24;

  ushort* qkvb = (ushort*)d_ws;                 // 3*QKVS bf16 (compact)
  ushort* qpb  = qkvb + 3 * QKVS;               // NT bf16
  ushort* kpb  = qpb + NT;                      // LKT bf16
  ushort* vTb  = kpb + LKT;                     // LKV bf16 ([bh][c][kpos], pitch LKP)
  float*  relb = (float*)(vTb + LKV);           // RELN fp32
  ushort* wqkvT = (ushort*)(relb + RELN);
  ushort* wprojT = wqkvT + (size_t)DIM * 3 * DIM;
  float*  wpoolT = (float*)(wprojT + (size_t)DIM * DIM);
  ushort* xb = qpb;                   // overlay: dead before pool writes qpb
  ushort* attn_outb = qkvb;           // overlay: qkvb dead after pools

  const int M = BATCH * NQ;  // 12544

  prep_kernel<<<NB_CAST + NB_TQKV + NB_TPROJ + NB_ZERO + NB_WPOOL, 256, 0, stream>>>(
      x, w_qkv, w_proj, pool_q_w, pool_k_w, pool_v_w,
      xb, wqkvT, wprojT, wpoolT, (uint4*)vTb, (int)(LKV * 2 / 16), M * DIM / 4);

  gemm_mfma<1><<<dim3(3 * DIM / 128, M / 128), 256, 0, stream>>>(
      xb, wqkvT, b_qkv, nullptr, qkvb, M, 3 * DIM, DIM);

  {
    pool_ln_row<1, 14, 0><<<(BATCH * NH * TT * 14) / 4, 256, 0, stream>>>(
        qkvb, qpb, wpoolT, norm_q_g, norm_q_b, 1.0f);
    pool_ln_row<2, 7, 0><<<(BATCH * NH * TT * 7) / 4, 256, 0, stream>>>(
        qkvb + QKVS, kpb, wpoolT + 27 * 64, norm_k_g, norm_k_b, SCALE);
    pool_ln_row<2, 7, 1><<<(BATCH * NH * TT * 7) / 4, 256, 0, stream>>>(
        qkvb + 2 * QKVS, vTb, wpoolT + 2 * 27 * 64, norm_v_g, norm_v_b, 1.0f);
  }

  rel_gemm<<<(BATCH * NH * NQ) / 128, 256, 0, stream>>>(
      qpb, rel_h, rel_w, rel_t, relb);

  attn_mfma<<<dim3(NQ / 32, BATCH * NH), 256, 0, stream>>>(qpb, kpb, vTb, relb, attn_outb);

  gemm_mfma<0><<<dim3(DIM / 128, M / 128), 256, 0, stream>>>(
      attn_outb, wprojT, b_proj, out, nullptr, M, DIM, DIM);
}